// Round 1
// baseline (4412.253 us; speedup 1.0000x reference)
//
#include <hip/hip_runtime.h>

#define NN 40000
#define NE 400000
#define NG 100
#define HH 3
#define HD 96

static constexpr int RROWS = 16;  // rows per block in node GEMMs

// ---------------------------------------------------------------- utilities

__device__ __forceinline__ float wsum(float v) {
#pragma unroll
    for (int m = 32; m >= 1; m >>= 1) v += __shfl_xor(v, m);
    return v;
}

// ---------------------------------------------------------------- GAT node GEMM
// z = h @ Wg  (N x DIN) @ (DIN x 3*DH), plus el/er head-wise dots with al/ar.
// block = 192 threads = 3 waves; wave w handles head w, lane d handles dim d.
template <int DIN, int DH>
__global__ __launch_bounds__(192) void gat_nodes(const float* __restrict__ h,
                                                 const float* __restrict__ W,
                                                 const float* __restrict__ al,
                                                 const float* __restrict__ ar,
                                                 float* __restrict__ z,
                                                 float* __restrict__ el,
                                                 float* __restrict__ er) {
    constexpr int CO = HH * DH;
    __shared__ float Wl[DIN * CO];
    __shared__ float alS[CO], arS[CO];
    __shared__ float hs[RROWS * DIN];
    const int tid = threadIdx.x;
    for (int i = tid; i < DIN * CO; i += 192) Wl[i] = W[i];
    for (int i = tid; i < CO; i += 192) { alS[i] = al[i]; arS[i] = ar[i]; }
    const int base = blockIdx.x * RROWS;
    const int nrow = min(RROWS, NN - base);
    for (int i = tid; i < nrow * DIN; i += 192) hs[i] = h[(size_t)base * DIN + i];
    __syncthreads();
    const int head = tid >> 6, d = tid & 63;
    const bool valid = d < DH;
    const int col = head * DH + d;
    for (int r = 0; r < nrow; ++r) {
        float acc = 0.f;
        if (valid) {
#pragma unroll
            for (int k = 0; k < DIN; ++k) acc += hs[r * DIN + k] * Wl[k * CO + col];
        }
        const int row = base + r;
        if (valid) z[(size_t)row * CO + col] = acc;
        float cl = valid ? acc * alS[col] : 0.f;
        float cr = valid ? acc * arS[col] : 0.f;
        cl = wsum(cl);
        cr = wsum(cr);
        if (d == 0) {
            el[row * HH + head] = cl;
            er[row * HH + head] = cr;
        }
    }
}

// ---------------------------------------------------------------- GAT edge phases
__global__ void gat_edge1(const int* __restrict__ src, const int* __restrict__ dst,
                          const float* __restrict__ el, const float* __restrict__ er,
                          float* __restrict__ ebuf, unsigned* __restrict__ menc) {
    int e = blockIdx.x * blockDim.x + threadIdx.x;
    if (e >= NE) return;
    int s = src[e], d = dst[e];
#pragma unroll
    for (int h = 0; h < HH; ++h) {
        float v = el[s * HH + h] + er[d * HH + h];
        v = v > 0.f ? v : 0.2f * v;  // leaky_relu 0.2
        ebuf[e * HH + h] = v;
        unsigned u = __float_as_uint(v);
        u = (u & 0x80000000u) ? ~u : (u | 0x80000000u);  // order-preserving encode
        atomicMax(&menc[d * HH + h], u);
    }
}

__global__ void gat_edge2(const int* __restrict__ dst, float* __restrict__ ebuf,
                          const unsigned* __restrict__ menc, float* __restrict__ den) {
    int e = blockIdx.x * blockDim.x + threadIdx.x;
    if (e >= NE) return;
    int d = dst[e];
#pragma unroll
    for (int h = 0; h < HH; ++h) {
        unsigned u = menc[d * HH + h];
        float m = (u & 0x80000000u) ? __uint_as_float(u & 0x7fffffffu) : __uint_as_float(~u);
        float ee = expf(ebuf[e * HH + h] - m);
        ebuf[e * HH + h] = ee;
        unsafeAtomicAdd(&den[d * HH + h], ee);
    }
}

__global__ void gat_alpha(const int* __restrict__ dst, float* __restrict__ ebuf,
                          const float* __restrict__ den, float* __restrict__ attn) {
    int e = blockIdx.x * blockDim.x + threadIdx.x;
    if (e >= NE) return;
    int d = dst[e];
    float a0 = ebuf[e * HH + 0] / den[d * HH + 0];
    float a1 = ebuf[e * HH + 1] / den[d * HH + 1];
    float a2 = ebuf[e * HH + 2] / den[d * HH + 2];
    ebuf[e * HH + 0] = a0;
    ebuf[e * HH + 1] = a1;
    ebuf[e * HH + 2] = a2;
    if (attn) attn[e] = fmaxf(fmaxf(a0, a1), a2);
}

// wave-per-edge scatter: out[dst] += alpha_h * z[src]
template <int DH>
__global__ __launch_bounds__(256) void gat_scatter(const int* __restrict__ src,
                                                   const int* __restrict__ dst,
                                                   const float* __restrict__ alpha,
                                                   const float* __restrict__ z,
                                                   float* __restrict__ outb) {
    constexpr int CO = HH * DH;
    int e = blockIdx.x * 4 + (threadIdx.x >> 6);
    if (e >= NE) return;
    int lane = threadIdx.x & 63;
    int s = src[e], d = dst[e];
    float a0 = alpha[e * HH + 0], a1 = alpha[e * HH + 1], a2 = alpha[e * HH + 2];
    const float* zr = z + (size_t)s * CO;
    float* orow = outb + (size_t)d * CO;
    for (int c = lane; c < CO; c += 64) {
        float a = (c < DH) ? a0 : ((c < 2 * DH) ? a1 : a2);
        unsafeAtomicAdd(&orow[c], a * zr[c]);
    }
}

// x[n][d] = maybe_relu( max_h(outb[n][h][d] + bg[h][d]) )
template <int DH>
__global__ void gat_epilogue(const float* __restrict__ outb, const float* __restrict__ bg,
                             float* __restrict__ x, int do_relu) {
    constexpr int CO = HH * DH;
    int idx = blockIdx.x * blockDim.x + threadIdx.x;
    if (idx >= NN * DH) return;
    int n = idx / DH, d = idx - n * DH;
    float m = -3.4e38f;
#pragma unroll
    for (int h = 0; h < HH; ++h)
        m = fmaxf(m, outb[(size_t)n * CO + h * DH + d] + bg[h * DH + d]);
    if (do_relu) m = fmaxf(m, 0.f);
    x[idx] = m;
}

// ---------------------------------------------------------------- GCN
__global__ void degree_k(const int* __restrict__ src, const int* __restrict__ dst,
                         float* __restrict__ dout, float* __restrict__ din) {
    int e = blockIdx.x * blockDim.x + threadIdx.x;
    if (e >= NE) return;
    unsafeAtomicAdd(&dout[src[e]], 1.f);
    unsafeAtomicAdd(&din[dst[e]], 1.f);
}

__global__ void rsqrt_k(float* __restrict__ a, float* __restrict__ b) {
    int n = blockIdx.x * blockDim.x + threadIdx.x;
    if (n >= NN) return;
    a[n] = 1.f / sqrtf(fmaxf(a[n], 1.f));
    b[n] = 1.f / sqrtf(fmaxf(b[n], 1.f));
}

// wave-per-edge: agg[dst] += rdout[src] * x[src]
template <int K>
__global__ __launch_bounds__(256) void gcn_scatter(const int* __restrict__ src,
                                                   const int* __restrict__ dst,
                                                   const float* __restrict__ x,
                                                   const float* __restrict__ rdout,
                                                   float* __restrict__ agg) {
    int e = blockIdx.x * 4 + (threadIdx.x >> 6);
    if (e >= NE) return;
    int lane = threadIdx.x & 63;
    int s = src[e], d = dst[e];
    float sc = rdout[s];
    const float* xr = x + (size_t)s * K;
    float* ar = agg + (size_t)d * K;
    for (int c = lane; c < K; c += 64) unsafeAtomicAdd(&ar[c], sc * xr[c]);
}

// out = relu( (in * rdin[row]) @ W + b ),  (N x K) @ (K x 96)
template <int K>
__global__ __launch_bounds__(192) void gcn_gemm(const float* __restrict__ in,
                                                const float* __restrict__ rdin,
                                                const float* __restrict__ W,
                                                const float* __restrict__ bias,
                                                float* __restrict__ out) {
    __shared__ float Wl[K * HD];
    __shared__ float hs[RROWS * K];
    __shared__ float bl[HD];
    const int tid = threadIdx.x;
    for (int i = tid; i < K * HD; i += 192) Wl[i] = W[i];
    if (tid < HD) bl[tid] = bias[tid];
    const int base = blockIdx.x * RROWS;
    const int nrow = min(RROWS, NN - base);
    for (int i = tid; i < nrow * K; i += 192) hs[i] = in[(size_t)base * K + i] * rdin[base + i / K];
    __syncthreads();
    const int co = tid % HD;
    const int grp = tid / HD;  // 0..1, each handles 8 rows
    float acc[8];
#pragma unroll
    for (int j = 0; j < 8; ++j) acc[j] = bl[co];
#pragma unroll
    for (int k = 0; k < K; ++k) {
        float w = Wl[k * HD + co];
#pragma unroll
        for (int j = 0; j < 8; ++j) acc[j] += hs[(grp * 8 + j) * K + k] * w;
    }
#pragma unroll
    for (int j = 0; j < 8; ++j) {
        int r = grp * 8 + j;
        if (r < nrow) out[(size_t)(base + r) * HD + co] = fmaxf(acc[j], 0.f);
    }
}

// ---------------------------------------------------------------- pooling + heads
__global__ void pool_k(const float* __restrict__ x, const int* __restrict__ gid,
                       float* __restrict__ s, float* __restrict__ c) {
    int idx = blockIdx.x * blockDim.x + threadIdx.x;
    if (idx >= NN * HD) return;
    int n = idx / HD, f = idx - n * HD;
    int g = gid[n];
    unsafeAtomicAdd(&s[g * HD + f], x[idx]);
    if (f == 0) unsafeAtomicAdd(&c[g], 1.f);
}

__global__ void weight_k(const float* __restrict__ x3, float* __restrict__ w) {
    int n = blockIdx.x * blockDim.x + threadIdx.x;
    if (n >= NN) return;
    w[n] = x3[(size_t)n * HD + 78];
}

__global__ __launch_bounds__(96) void final_k(
    const float* __restrict__ s1, const float* __restrict__ s2, const float* __restrict__ s3,
    const float* __restrict__ c1, const float* __restrict__ c2, const float* __restrict__ c3,
    const float* __restrict__ Wr1, const float* __restrict__ br1,
    const float* __restrict__ Wr2, const float* __restrict__ br2,
    const float* __restrict__ Wcl, const float* __restrict__ bcl,
    float* __restrict__ r1, float* __restrict__ r2, float* __restrict__ cls,
    float* __restrict__ hg3) {
    __shared__ float sh[HD];
    int g = blockIdx.x, f = threadIdx.x;
    float h1v = s1[g * HD + f] / fmaxf(c1[g], 1.f);
    float h2v = s2[g * HD + f] / fmaxf(c2[g], 1.f);
    float h3v = s3[g * HD + f] / fmaxf(c3[g], 1.f);
    hg3[g * HD + f] = h3v;
    sh[f] = h1v * Wr1[f];
    __syncthreads();
    if (f == 0) {
        float t = 0.f;
        for (int i = 0; i < HD; ++i) t += sh[i];
        r1[g] = t + br1[0];
    }
    __syncthreads();
    sh[f] = h2v * Wr2[f];
    __syncthreads();
    if (f == 0) {
        float t = 0.f;
        for (int i = 0; i < HD; ++i) t += sh[i];
        r2[g] = t + br2[0];
    }
    __syncthreads();
    for (int c = 0; c < 10; ++c) {
        sh[f] = h3v * Wcl[f * 10 + c];
        __syncthreads();
        if (f == 0) {
            float t = 0.f;
            for (int i = 0; i < HD; ++i) t += sh[i];
            cls[g * 10 + c] = t + bcl[c];
        }
        __syncthreads();
    }
}

// ---------------------------------------------------------------- host side

struct WS {
    float *z, *outb, *xbuf, *ybuf, *el, *er, *den, *ebuf, *rdout, *rdin;
    unsigned* menc;
};

template <int DH>
static void run_graph(const float* h, const int* src, const int* dst, const int* gid,
                      const float* Wg, const float* al, const float* ar, const float* bg,
                      const float* Wf, const float* bf, const float* W2, const float* b2,
                      int relu_epi, float* attn, float* pool_s, float* pool_c,
                      const WS& w, hipStream_t st) {
    constexpr int CO = HH * DH;
    const int nb = (NN + RROWS - 1) / RROWS;
    const int eb = (NE + 255) / 256;
    const int sb = (NE + 3) / 4;

    gat_nodes<DH, DH><<<nb, 192, 0, st>>>(h, Wg, al, ar, w.z, w.el, w.er);
    hipMemsetAsync(w.menc, 0, (size_t)NN * HH * sizeof(unsigned), st);
    hipMemsetAsync(w.den, 0, (size_t)NN * HH * sizeof(float), st);
    hipMemsetAsync(w.outb, 0, (size_t)NN * CO * sizeof(float), st);
    gat_edge1<<<eb, 256, 0, st>>>(src, dst, w.el, w.er, w.ebuf, w.menc);
    gat_edge2<<<eb, 256, 0, st>>>(dst, w.ebuf, w.menc, w.den);
    gat_alpha<<<eb, 256, 0, st>>>(dst, w.ebuf, w.den, attn);
    gat_scatter<DH><<<sb, 256, 0, st>>>(src, dst, w.ebuf, w.z, w.outb);
    gat_epilogue<DH><<<(NN * DH + 255) / 256, 256, 0, st>>>(w.outb, bg, w.xbuf, relu_epi);

    hipMemsetAsync(w.rdout, 0, NN * sizeof(float), st);
    hipMemsetAsync(w.rdin, 0, NN * sizeof(float), st);
    degree_k<<<eb, 256, 0, st>>>(src, dst, w.rdout, w.rdin);
    rsqrt_k<<<(NN + 255) / 256, 256, 0, st>>>(w.rdout, w.rdin);

    // GCN layer 1: xbuf (width DH) -> agg ybuf (width DH) -> xbuf (width 96)
    hipMemsetAsync(w.ybuf, 0, (size_t)NN * DH * sizeof(float), st);
    gcn_scatter<DH><<<sb, 256, 0, st>>>(src, dst, w.xbuf, w.rdout, w.ybuf);
    gcn_gemm<DH><<<nb, 192, 0, st>>>(w.ybuf, w.rdin, Wf, bf, w.xbuf);
    // GCN layer 2: xbuf (96) -> ybuf (96) -> xbuf (96)
    hipMemsetAsync(w.ybuf, 0, (size_t)NN * HD * sizeof(float), st);
    gcn_scatter<HD><<<sb, 256, 0, st>>>(src, dst, w.xbuf, w.rdout, w.ybuf);
    gcn_gemm<HD><<<nb, 192, 0, st>>>(w.ybuf, w.rdin, W2, b2, w.xbuf);

    hipMemsetAsync(pool_s, 0, NG * HD * sizeof(float), st);
    hipMemsetAsync(pool_c, 0, NG * sizeof(float), st);
    pool_k<<<(NN * HD + 255) / 256, 256, 0, st>>>(w.xbuf, gid, pool_s, pool_c);
}

extern "C" void kernel_launch(void* const* d_in, const int* in_sizes, int n_in,
                              void* d_out, int out_size, void* d_ws, size_t ws_size,
                              hipStream_t stream) {
    (void)in_sizes; (void)n_in; (void)out_size; (void)ws_size;
    const float* h1 = (const float*)d_in[0];
    const float* h2 = (const float*)d_in[1];
    const float* h3 = (const float*)d_in[2];
    const int* src1 = (const int*)d_in[3];
    const int* dst1 = (const int*)d_in[4];
    const int* gid1 = (const int*)d_in[5];
    const int* src2 = (const int*)d_in[6];
    const int* dst2 = (const int*)d_in[7];
    const int* gid2 = (const int*)d_in[8];
    const int* src3 = (const int*)d_in[9];
    const int* dst3 = (const int*)d_in[10];
    const int* gid3 = (const int*)d_in[11];
    const float* Wg1 = (const float*)d_in[12];
    const float* al1 = (const float*)d_in[13];
    const float* ar1 = (const float*)d_in[14];
    const float* bg1 = (const float*)d_in[15];
    const float* Wg2 = (const float*)d_in[16];
    const float* al2 = (const float*)d_in[17];
    const float* ar2 = (const float*)d_in[18];
    const float* bg2 = (const float*)d_in[19];
    const float* Wc1 = (const float*)d_in[20];
    const float* bc1 = (const float*)d_in[21];
    const float* Wc2 = (const float*)d_in[22];
    const float* bc2 = (const float*)d_in[23];
    const float* Wc3 = (const float*)d_in[24];
    const float* bc3 = (const float*)d_in[25];
    const float* Wr1 = (const float*)d_in[26];
    const float* br1 = (const float*)d_in[27];
    const float* Wr2 = (const float*)d_in[28];
    const float* br2 = (const float*)d_in[29];
    const float* Wcl = (const float*)d_in[30];
    const float* bcl = (const float*)d_in[31];

    float* out = (float*)d_out;
    float* o_r1 = out + 0;
    float* o_r2 = out + 100;
    float* o_cls = out + 200;
    float* o_attn1 = out + 1200;
    float* o_attn3 = out + 401200;
    float* o_weight = out + 801200;
    float* o_hg3 = out + 841200;

    // workspace layout (floats)
    float* ws = (float*)d_ws;
    size_t off = 0;
    WS w;
    w.z = ws + off;     off += (size_t)NN * 192;
    w.outb = ws + off;  off += (size_t)NN * 192;
    w.xbuf = ws + off;  off += (size_t)NN * HD;
    w.ybuf = ws + off;  off += (size_t)NN * HD;
    w.el = ws + off;    off += (size_t)NN * HH;
    w.er = ws + off;    off += (size_t)NN * HH;
    w.menc = (unsigned*)(ws + off); off += (size_t)NN * HH;
    w.den = ws + off;   off += (size_t)NN * HH;
    w.ebuf = ws + off;  off += (size_t)NE * HH;
    w.rdout = ws + off; off += NN;
    w.rdin = ws + off;  off += NN;
    float* s1 = ws + off; off += NG * HD;
    float* s2 = ws + off; off += NG * HD;
    float* s3 = ws + off; off += NG * HD;
    float* c1 = ws + off; off += NG;
    float* c2 = ws + off; off += NG;
    float* c3 = ws + off; off += NG;

    // graph 1: GAT(Wg1, Dh=63) -> relu(max) -> GCN(Wc3) -> GCN(Wc2), attn out
    run_graph<63>(h1, src1, dst1, gid1, Wg1, al1, ar1, bg1, Wc3, bc3, Wc2, bc2,
                  1, o_attn1, s1, c1, w, stream);
    // graph 2: same GAT weights, no relu on max, no attn out
    run_graph<63>(h2, src2, dst2, gid2, Wg1, al1, ar1, bg1, Wc3, bc3, Wc2, bc2,
                  0, nullptr, s2, c2, w, stream);
    // graph 3: GAT(Wg2, Dh=64), no relu on max, attn out; GCN(Wc1) then GCN(Wc2)
    run_graph<64>(h3, src3, dst3, gid3, Wg2, al2, ar2, bg2, Wc1, bc1, Wc2, bc2,
                  0, o_attn3, s3, c3, w, stream);

    weight_k<<<(NN + 255) / 256, 256, 0, stream>>>(w.xbuf, o_weight);
    final_k<<<NG, 96, 0, stream>>>(s1, s2, s3, c1, c2, c3, Wr1, br1, Wr2, br2,
                                   Wcl, bcl, o_r1, o_r2, o_cls, o_hg3);
}

// Round 2
// 3583.051 us; speedup vs baseline: 1.2314x; 1.2314x over previous
//
#include <hip/hip_runtime.h>

#define NN 40000
#define NE 400000
#define NG 100
#define HH 3
#define HD 96

static constexpr int RROWS = 16;  // rows per block in node GEMMs

// ---------------------------------------------------------------- utilities

__device__ __forceinline__ float wsum(float v) {
#pragma unroll
    for (int m = 32; m >= 1; m >>= 1) v += __shfl_xor(v, m);
    return v;
}

// ---------------------------------------------------------------- GAT node GEMM
// z = h @ Wg  (N x DIN) @ (DIN x 3*DH), plus el/er head-wise dots with al/ar.
// block = 192 threads = 3 waves; wave w handles head w, lane d handles dim d.
template <int DIN, int DH>
__global__ __launch_bounds__(192) void gat_nodes(const float* __restrict__ h,
                                                 const float* __restrict__ W,
                                                 const float* __restrict__ al,
                                                 const float* __restrict__ ar,
                                                 float* __restrict__ z,
                                                 float* __restrict__ el,
                                                 float* __restrict__ er) {
    constexpr int CO = HH * DH;
    __shared__ float Wl[DIN * CO];
    __shared__ float alS[CO], arS[CO];
    __shared__ float hs[RROWS * DIN];
    const int tid = threadIdx.x;
    for (int i = tid; i < DIN * CO; i += 192) Wl[i] = W[i];
    for (int i = tid; i < CO; i += 192) { alS[i] = al[i]; arS[i] = ar[i]; }
    const int base = blockIdx.x * RROWS;
    const int nrow = min(RROWS, NN - base);
    for (int i = tid; i < nrow * DIN; i += 192) hs[i] = h[(size_t)base * DIN + i];
    __syncthreads();
    const int head = tid >> 6, d = tid & 63;
    const bool valid = d < DH;
    const int col = head * DH + d;
    for (int r = 0; r < nrow; ++r) {
        float acc = 0.f;
        if (valid) {
#pragma unroll 4
            for (int k = 0; k < DIN; ++k) acc += hs[r * DIN + k] * Wl[k * CO + col];
        }
        const int row = base + r;
        if (valid) z[(size_t)row * CO + col] = acc;
        float cl = valid ? acc * alS[col] : 0.f;
        float cr = valid ? acc * arS[col] : 0.f;
        cl = wsum(cl);
        cr = wsum(cr);
        if (d == 0) {
            el[row * HH + head] = cl;
            er[row * HH + head] = cr;
        }
    }
}

// ---------------------------------------------------------------- GAT edge phases
__global__ void gat_edge1(const int* __restrict__ src, const int* __restrict__ dst,
                          const float* __restrict__ el, const float* __restrict__ er,
                          float* __restrict__ ebuf, unsigned* __restrict__ menc) {
    int e = blockIdx.x * blockDim.x + threadIdx.x;
    if (e >= NE) return;
    int s = src[e], d = dst[e];
#pragma unroll
    for (int h = 0; h < HH; ++h) {
        float v = el[s * HH + h] + er[d * HH + h];
        v = v > 0.f ? v : 0.2f * v;  // leaky_relu 0.2
        ebuf[e * HH + h] = v;
        unsigned u = __float_as_uint(v);
        u = (u & 0x80000000u) ? ~u : (u | 0x80000000u);  // order-preserving encode
        atomicMax(&menc[d * HH + h], u);
    }
}

__global__ void gat_edge2(const int* __restrict__ dst, float* __restrict__ ebuf,
                          const unsigned* __restrict__ menc, float* __restrict__ den) {
    int e = blockIdx.x * blockDim.x + threadIdx.x;
    if (e >= NE) return;
    int d = dst[e];
#pragma unroll
    for (int h = 0; h < HH; ++h) {
        unsigned u = menc[d * HH + h];
        float m = (u & 0x80000000u) ? __uint_as_float(u & 0x7fffffffu) : __uint_as_float(~u);
        float ee = expf(ebuf[e * HH + h] - m);
        ebuf[e * HH + h] = ee;
        unsafeAtomicAdd(&den[d * HH + h], ee);
    }
}

// wave-per-edge scatter with fused alpha: alpha = ee/den[dst];
// out[dst] += alpha_h * z[src]; attn[e] = max_h alpha (lane 0)
template <int DH>
__global__ __launch_bounds__(256) void gat_scatter(const int* __restrict__ src,
                                                   const int* __restrict__ dst,
                                                   const float* __restrict__ ebuf,
                                                   const float* __restrict__ den,
                                                   const float* __restrict__ z,
                                                   float* __restrict__ outb,
                                                   float* __restrict__ attn) {
    constexpr int CO = HH * DH;
    int e = blockIdx.x * 4 + (threadIdx.x >> 6);
    if (e >= NE) return;
    int lane = threadIdx.x & 63;
    int s = src[e], d = dst[e];
    float a0 = ebuf[e * HH + 0] / den[d * HH + 0];
    float a1 = ebuf[e * HH + 1] / den[d * HH + 1];
    float a2 = ebuf[e * HH + 2] / den[d * HH + 2];
    if (attn && lane == 0) attn[e] = fmaxf(fmaxf(a0, a1), a2);
    const float* zr = z + (size_t)s * CO;
    float* orow = outb + (size_t)d * CO;
    for (int c = lane; c < CO; c += 64) {
        float a = (c < DH) ? a0 : ((c < 2 * DH) ? a1 : a2);
        unsafeAtomicAdd(&orow[c], a * zr[c]);
    }
}

// x[n][d] = maybe_relu( max_h(outb[n][h][d] + bg[h][d]) )
template <int DH>
__global__ void gat_epilogue(const float* __restrict__ outb, const float* __restrict__ bg,
                             float* __restrict__ x, int do_relu) {
    constexpr int CO = HH * DH;
    int idx = blockIdx.x * blockDim.x + threadIdx.x;
    if (idx >= NN * DH) return;
    int n = idx / DH, d = idx - n * DH;
    float m = -3.4e38f;
#pragma unroll
    for (int h = 0; h < HH; ++h)
        m = fmaxf(m, outb[(size_t)n * CO + h * DH + d] + bg[h * DH + d]);
    if (do_relu) m = fmaxf(m, 0.f);
    x[idx] = m;
}

// ---------------------------------------------------------------- GCN
__global__ void degree_k(const int* __restrict__ src, const int* __restrict__ dst,
                         float* __restrict__ dout, float* __restrict__ din) {
    int e = blockIdx.x * blockDim.x + threadIdx.x;
    if (e >= NE) return;
    unsafeAtomicAdd(&dout[src[e]], 1.f);
    unsafeAtomicAdd(&din[dst[e]], 1.f);
}

__global__ void rsqrt_k(float* __restrict__ a, float* __restrict__ b) {
    int n = blockIdx.x * blockDim.x + threadIdx.x;
    if (n >= NN) return;
    a[n] = 1.f / sqrtf(fmaxf(a[n], 1.f));
    b[n] = 1.f / sqrtf(fmaxf(b[n], 1.f));
}

// wave-per-edge: agg[dst] += rdout[src] * x[src]
template <int K>
__global__ __launch_bounds__(256) void gcn_scatter(const int* __restrict__ src,
                                                   const int* __restrict__ dst,
                                                   const float* __restrict__ x,
                                                   const float* __restrict__ rdout,
                                                   float* __restrict__ agg) {
    int e = blockIdx.x * 4 + (threadIdx.x >> 6);
    if (e >= NE) return;
    int lane = threadIdx.x & 63;
    int s = src[e], d = dst[e];
    float sc = rdout[s];
    const float* xr = x + (size_t)s * K;
    float* ar = agg + (size_t)d * K;
    for (int c = lane; c < K; c += 64) unsafeAtomicAdd(&ar[c], sc * xr[c]);
}

// out = relu( (in * rdin[row]) @ W + b ),  (N x K) @ (K x 96)
// NOTE: k-loop unroll bounded to 4 — full unroll spilled (VGPR=256,
// 790 MB scratch round-trip per dispatch, 322 us; see round-1 counters).
template <int K>
__global__ __launch_bounds__(192) void gcn_gemm(const float* __restrict__ in,
                                                const float* __restrict__ rdin,
                                                const float* __restrict__ W,
                                                const float* __restrict__ bias,
                                                float* __restrict__ out) {
    __shared__ float Wl[K * HD];
    __shared__ float hs[RROWS * K];
    __shared__ float bl[HD];
    const int tid = threadIdx.x;
    for (int i = tid; i < K * HD; i += 192) Wl[i] = W[i];
    if (tid < HD) bl[tid] = bias[tid];
    const int base = blockIdx.x * RROWS;
    const int nrow = min(RROWS, NN - base);
    for (int i = tid; i < nrow * K; i += 192) hs[i] = in[(size_t)base * K + i] * rdin[base + i / K];
    __syncthreads();
    const int co = tid % HD;
    const int grp = tid / HD;  // 0..1, each handles 8 rows
    float acc[8];
#pragma unroll
    for (int j = 0; j < 8; ++j) acc[j] = bl[co];
#pragma unroll 4
    for (int k = 0; k < K; ++k) {
        float w = Wl[k * HD + co];
#pragma unroll
        for (int j = 0; j < 8; ++j) acc[j] += hs[(grp * 8 + j) * K + k] * w;
    }
#pragma unroll
    for (int j = 0; j < 8; ++j) {
        int r = grp * 8 + j;
        if (r < nrow) out[(size_t)(base + r) * HD + co] = fmaxf(acc[j], 0.f);
    }
}

// ---------------------------------------------------------------- pooling + heads
__global__ void pool_k(const float* __restrict__ x, const int* __restrict__ gid,
                       float* __restrict__ s, float* __restrict__ c) {
    int idx = blockIdx.x * blockDim.x + threadIdx.x;
    if (idx >= NN * HD) return;
    int n = idx / HD, f = idx - n * HD;
    int g = gid[n];
    unsafeAtomicAdd(&s[g * HD + f], x[idx]);
    if (f == 0) unsafeAtomicAdd(&c[g], 1.f);
}

__global__ void weight_k(const float* __restrict__ x3, float* __restrict__ w) {
    int n = blockIdx.x * blockDim.x + threadIdx.x;
    if (n >= NN) return;
    w[n] = x3[(size_t)n * HD + 78];
}

__global__ __launch_bounds__(96) void final_k(
    const float* __restrict__ s1, const float* __restrict__ s2, const float* __restrict__ s3,
    const float* __restrict__ c1, const float* __restrict__ c2, const float* __restrict__ c3,
    const float* __restrict__ Wr1, const float* __restrict__ br1,
    const float* __restrict__ Wr2, const float* __restrict__ br2,
    const float* __restrict__ Wcl, const float* __restrict__ bcl,
    float* __restrict__ r1, float* __restrict__ r2, float* __restrict__ cls,
    float* __restrict__ hg3) {
    __shared__ float sh[HD];
    int g = blockIdx.x, f = threadIdx.x;
    float h1v = s1[g * HD + f] / fmaxf(c1[g], 1.f);
    float h2v = s2[g * HD + f] / fmaxf(c2[g], 1.f);
    float h3v = s3[g * HD + f] / fmaxf(c3[g], 1.f);
    hg3[g * HD + f] = h3v;
    sh[f] = h1v * Wr1[f];
    __syncthreads();
    if (f == 0) {
        float t = 0.f;
        for (int i = 0; i < HD; ++i) t += sh[i];
        r1[g] = t + br1[0];
    }
    __syncthreads();
    sh[f] = h2v * Wr2[f];
    __syncthreads();
    if (f == 0) {
        float t = 0.f;
        for (int i = 0; i < HD; ++i) t += sh[i];
        r2[g] = t + br2[0];
    }
    __syncthreads();
    for (int c = 0; c < 10; ++c) {
        sh[f] = h3v * Wcl[f * 10 + c];
        __syncthreads();
        if (f == 0) {
            float t = 0.f;
            for (int i = 0; i < HD; ++i) t += sh[i];
            cls[g * 10 + c] = t + bcl[c];
        }
        __syncthreads();
    }
}

// ---------------------------------------------------------------- host side

struct WS {
    float *z, *outb, *xbuf, *ybuf, *el, *er, *den, *ebuf, *rdout, *rdin;
    unsigned* menc;
};

template <int DH>
static void run_graph(const float* h, const int* src, const int* dst, const int* gid,
                      const float* Wg, const float* al, const float* ar, const float* bg,
                      const float* Wf, const float* bf, const float* W2, const float* b2,
                      int relu_epi, float* attn, float* pool_s, float* pool_c,
                      const WS& w, hipStream_t st) {
    constexpr int CO = HH * DH;
    const int nb = (NN + RROWS - 1) / RROWS;
    const int eb = (NE + 255) / 256;
    const int sb = (NE + 3) / 4;

    gat_nodes<DH, DH><<<nb, 192, 0, st>>>(h, Wg, al, ar, w.z, w.el, w.er);
    hipMemsetAsync(w.menc, 0, (size_t)NN * HH * sizeof(unsigned), st);
    hipMemsetAsync(w.den, 0, (size_t)NN * HH * sizeof(float), st);
    hipMemsetAsync(w.outb, 0, (size_t)NN * CO * sizeof(float), st);
    gat_edge1<<<eb, 256, 0, st>>>(src, dst, w.el, w.er, w.ebuf, w.menc);
    gat_edge2<<<eb, 256, 0, st>>>(dst, w.ebuf, w.menc, w.den);
    gat_scatter<DH><<<sb, 256, 0, st>>>(src, dst, w.ebuf, w.den, w.z, w.outb, attn);
    gat_epilogue<DH><<<(NN * DH + 255) / 256, 256, 0, st>>>(w.outb, bg, w.xbuf, relu_epi);

    hipMemsetAsync(w.rdout, 0, NN * sizeof(float), st);
    hipMemsetAsync(w.rdin, 0, NN * sizeof(float), st);
    degree_k<<<eb, 256, 0, st>>>(src, dst, w.rdout, w.rdin);
    rsqrt_k<<<(NN + 255) / 256, 256, 0, st>>>(w.rdout, w.rdin);

    // GCN layer 1: xbuf (width DH) -> agg ybuf (width DH) -> xbuf (width 96)
    hipMemsetAsync(w.ybuf, 0, (size_t)NN * DH * sizeof(float), st);
    gcn_scatter<DH><<<sb, 256, 0, st>>>(src, dst, w.xbuf, w.rdout, w.ybuf);
    gcn_gemm<DH><<<nb, 192, 0, st>>>(w.ybuf, w.rdin, Wf, bf, w.xbuf);
    // GCN layer 2: xbuf (96) -> ybuf (96) -> xbuf (96)
    hipMemsetAsync(w.ybuf, 0, (size_t)NN * HD * sizeof(float), st);
    gcn_scatter<HD><<<sb, 256, 0, st>>>(src, dst, w.xbuf, w.rdout, w.ybuf);
    gcn_gemm<HD><<<nb, 192, 0, st>>>(w.ybuf, w.rdin, W2, b2, w.xbuf);

    hipMemsetAsync(pool_s, 0, NG * HD * sizeof(float), st);
    hipMemsetAsync(pool_c, 0, NG * sizeof(float), st);
    pool_k<<<(NN * HD + 255) / 256, 256, 0, st>>>(w.xbuf, gid, pool_s, pool_c);
}

extern "C" void kernel_launch(void* const* d_in, const int* in_sizes, int n_in,
                              void* d_out, int out_size, void* d_ws, size_t ws_size,
                              hipStream_t stream) {
    (void)in_sizes; (void)n_in; (void)out_size; (void)ws_size;
    const float* h1 = (const float*)d_in[0];
    const float* h2 = (const float*)d_in[1];
    const float* h3 = (const float*)d_in[2];
    const int* src1 = (const int*)d_in[3];
    const int* dst1 = (const int*)d_in[4];
    const int* gid1 = (const int*)d_in[5];
    const int* src2 = (const int*)d_in[6];
    const int* dst2 = (const int*)d_in[7];
    const int* gid2 = (const int*)d_in[8];
    const int* src3 = (const int*)d_in[9];
    const int* dst3 = (const int*)d_in[10];
    const int* gid3 = (const int*)d_in[11];
    const float* Wg1 = (const float*)d_in[12];
    const float* al1 = (const float*)d_in[13];
    const float* ar1 = (const float*)d_in[14];
    const float* bg1 = (const float*)d_in[15];
    const float* Wg2 = (const float*)d_in[16];
    const float* al2 = (const float*)d_in[17];
    const float* ar2 = (const float*)d_in[18];
    const float* bg2 = (const float*)d_in[19];
    const float* Wc1 = (const float*)d_in[20];
    const float* bc1 = (const float*)d_in[21];
    const float* Wc2 = (const float*)d_in[22];
    const float* bc2 = (const float*)d_in[23];
    const float* Wc3 = (const float*)d_in[24];
    const float* bc3 = (const float*)d_in[25];
    const float* Wr1 = (const float*)d_in[26];
    const float* br1 = (const float*)d_in[27];
    const float* Wr2 = (const float*)d_in[28];
    const float* br2 = (const float*)d_in[29];
    const float* Wcl = (const float*)d_in[30];
    const float* bcl = (const float*)d_in[31];

    float* out = (float*)d_out;
    float* o_r1 = out + 0;
    float* o_r2 = out + 100;
    float* o_cls = out + 200;
    float* o_attn1 = out + 1200;
    float* o_attn3 = out + 401200;
    float* o_weight = out + 801200;
    float* o_hg3 = out + 841200;

    // workspace layout (floats)
    float* ws = (float*)d_ws;
    size_t off = 0;
    WS w;
    w.z = ws + off;     off += (size_t)NN * 192;
    w.outb = ws + off;  off += (size_t)NN * 192;
    w.xbuf = ws + off;  off += (size_t)NN * HD;
    w.ybuf = ws + off;  off += (size_t)NN * HD;
    w.el = ws + off;    off += (size_t)NN * HH;
    w.er = ws + off;    off += (size_t)NN * HH;
    w.menc = (unsigned*)(ws + off); off += (size_t)NN * HH;
    w.den = ws + off;   off += (size_t)NN * HH;
    w.ebuf = ws + off;  off += (size_t)NE * HH;
    w.rdout = ws + off; off += NN;
    w.rdin = ws + off;  off += NN;
    float* s1 = ws + off; off += NG * HD;
    float* s2 = ws + off; off += NG * HD;
    float* s3 = ws + off; off += NG * HD;
    float* c1 = ws + off; off += NG;
    float* c2 = ws + off; off += NG;
    float* c3 = ws + off; off += NG;

    // graph 1: GAT(Wg1, Dh=63) -> relu(max) -> GCN(Wc3) -> GCN(Wc2), attn out
    run_graph<63>(h1, src1, dst1, gid1, Wg1, al1, ar1, bg1, Wc3, bc3, Wc2, bc2,
                  1, o_attn1, s1, c1, w, stream);
    // graph 2: same GAT weights, no relu on max, no attn out
    run_graph<63>(h2, src2, dst2, gid2, Wg1, al1, ar1, bg1, Wc3, bc3, Wc2, bc2,
                  0, nullptr, s2, c2, w, stream);
    // graph 3: GAT(Wg2, Dh=64), no relu on max, attn out; GCN(Wc1) then GCN(Wc2)
    run_graph<64>(h3, src3, dst3, gid3, Wg2, al2, ar2, bg2, Wc1, bc1, Wc2, bc2,
                  0, o_attn3, s3, c3, w, stream);

    weight_k<<<(NN + 255) / 256, 256, 0, stream>>>(w.xbuf, o_weight);
    final_k<<<NG, 96, 0, stream>>>(s1, s2, s3, c1, c2, c3, Wr1, br1, Wr2, br2,
                                   Wcl, bcl, o_r1, o_r2, o_cls, o_hg3);
}

// Round 4
// 2400.714 us; speedup vs baseline: 1.8379x; 1.4925x over previous
//
#include <hip/hip_runtime.h>

#define NN 40000
#define NE 400000
#define NG 100
#define HH 3
#define HD 96

static constexpr int RROWS = 16;  // rows per block in node GEMMs

// ---------------------------------------------------------------- utilities

__device__ __forceinline__ float wsum(float v) {
#pragma unroll
    for (int m = 32; m >= 1; m >>= 1) v += __shfl_xor(v, m);
    return v;
}

// ---------------------------------------------------------------- GAT node GEMM
// z = h @ Wg  (N x DIN) @ (DIN x 3*DH), plus el/er head-wise dots with al/ar.
template <int DIN, int DH>
__global__ __launch_bounds__(192) void gat_nodes(const float* __restrict__ h,
                                                 const float* __restrict__ W,
                                                 const float* __restrict__ al,
                                                 const float* __restrict__ ar,
                                                 float* __restrict__ z,
                                                 float* __restrict__ el,
                                                 float* __restrict__ er) {
    constexpr int CO = HH * DH;
    __shared__ float Wl[DIN * CO];
    __shared__ float alS[CO], arS[CO];
    __shared__ float hs[RROWS * DIN];
    const int tid = threadIdx.x;
    for (int i = tid; i < DIN * CO; i += 192) Wl[i] = W[i];
    for (int i = tid; i < CO; i += 192) { alS[i] = al[i]; arS[i] = ar[i]; }
    const int base = blockIdx.x * RROWS;
    const int nrow = min(RROWS, NN - base);
    for (int i = tid; i < nrow * DIN; i += 192) hs[i] = h[(size_t)base * DIN + i];
    __syncthreads();
    const int head = tid >> 6, d = tid & 63;
    const bool valid = d < DH;
    const int col = head * DH + d;
    for (int r = 0; r < nrow; ++r) {
        float acc = 0.f;
        if (valid) {
#pragma unroll 4
            for (int k = 0; k < DIN; ++k) acc += hs[r * DIN + k] * Wl[k * CO + col];
        }
        const int row = base + r;
        if (valid) z[(size_t)row * CO + col] = acc;
        float cl = valid ? acc * alS[col] : 0.f;
        float cr = valid ? acc * arS[col] : 0.f;
        cl = wsum(cl);
        cr = wsum(cr);
        if (d == 0) {
            el[row * HH + head] = cl;
            er[row * HH + head] = cr;
        }
    }
}

// ---------------------------------------------------------------- CSR build
__global__ void hist_k(const int* __restrict__ src, const int* __restrict__ dst,
                       int* __restrict__ cin, int* __restrict__ cout) {
    int e = blockIdx.x * blockDim.x + threadIdx.x;
    if (e >= NE) return;
    atomicAdd(&cin[dst[e]], 1);
    atomicAdd(&cout[src[e]], 1);
}

// single-block exclusive scan of cin -> rowstart (+ cursor copy)
__global__ __launch_bounds__(1024) void scan_k(const int* __restrict__ cin,
                                               int* __restrict__ rowstart,
                                               int* __restrict__ cursor) {
    __shared__ int part[1024];
    const int t = threadIdx.x;
    const int lo = t * 40;
    const int hi = min(lo + 40, NN);
    int s = 0;
    for (int i = lo; i < hi; ++i) s += cin[i];
    part[t] = s;
    __syncthreads();
    for (int off = 1; off < 1024; off <<= 1) {
        int u = (t >= off) ? part[t - off] : 0;
        __syncthreads();
        part[t] += u;
        __syncthreads();
    }
    int base = part[t] - s;  // exclusive prefix of this thread's chunk
    for (int i = lo; i < hi; ++i) {
        rowstart[i] = base;
        cursor[i] = base;
        base += cin[i];
    }
}

__global__ void fill_k(const int* __restrict__ src, const int* __restrict__ dst,
                       int* __restrict__ cursor, int* __restrict__ esrc,
                       int* __restrict__ eorig) {
    int e = blockIdx.x * blockDim.x + threadIdx.x;
    if (e >= NE) return;
    int pos = atomicAdd(&cursor[dst[e]], 1);
    esrc[pos] = src[e];
    eorig[pos] = e;
}

__global__ void rsqrt_k(const int* __restrict__ cin, const int* __restrict__ cout,
                        float* __restrict__ rdin, float* __restrict__ rdout) {
    int n = blockIdx.x * blockDim.x + threadIdx.x;
    if (n >= NN) return;
    rdin[n] = 1.f / sqrtf((float)max(cin[n], 1));
    rdout[n] = 1.f / sqrtf((float)max(cout[n], 1));
}

// ---------------------------------------------------------------- GAT softmax (per dst node, serial over CSR row)
__global__ void gat_softmax(const int* __restrict__ rowstart, const int* __restrict__ cnt,
                            const int* __restrict__ esrc, const int* __restrict__ eorig,
                            const float* __restrict__ el, const float* __restrict__ er,
                            float* __restrict__ aebuf, float* __restrict__ attn) {
    int n = blockIdx.x * blockDim.x + threadIdx.x;
    if (n >= NN) return;
    const int s0 = rowstart[n];
    const int deg = cnt[n];
    if (deg == 0) return;
    const float er0 = er[n * HH + 0], er1 = er[n * HH + 1], er2 = er[n * HH + 2];
    float m0 = -3.4e38f, m1 = -3.4e38f, m2 = -3.4e38f;
    for (int i = 0; i < deg; ++i) {
        int s = esrc[s0 + i];
        float v0 = el[s * HH + 0] + er0;
        float v1 = el[s * HH + 1] + er1;
        float v2 = el[s * HH + 2] + er2;
        v0 = v0 > 0.f ? v0 : 0.2f * v0;
        v1 = v1 > 0.f ? v1 : 0.2f * v1;
        v2 = v2 > 0.f ? v2 : 0.2f * v2;
        aebuf[(size_t)(s0 + i) * HH + 0] = v0;
        aebuf[(size_t)(s0 + i) * HH + 1] = v1;
        aebuf[(size_t)(s0 + i) * HH + 2] = v2;
        m0 = fmaxf(m0, v0); m1 = fmaxf(m1, v1); m2 = fmaxf(m2, v2);
    }
    float d0 = 0.f, d1 = 0.f, d2 = 0.f;
    for (int i = 0; i < deg; ++i) {
        float p0 = expf(aebuf[(size_t)(s0 + i) * HH + 0] - m0);
        float p1 = expf(aebuf[(size_t)(s0 + i) * HH + 1] - m1);
        float p2 = expf(aebuf[(size_t)(s0 + i) * HH + 2] - m2);
        aebuf[(size_t)(s0 + i) * HH + 0] = p0;
        aebuf[(size_t)(s0 + i) * HH + 1] = p1;
        aebuf[(size_t)(s0 + i) * HH + 2] = p2;
        d0 += p0; d1 += p1; d2 += p2;
    }
    const float i0 = 1.f / d0, i1 = 1.f / d1, i2 = 1.f / d2;
    for (int i = 0; i < deg; ++i) {
        float a0 = aebuf[(size_t)(s0 + i) * HH + 0] * i0;
        float a1 = aebuf[(size_t)(s0 + i) * HH + 1] * i1;
        float a2 = aebuf[(size_t)(s0 + i) * HH + 2] * i2;
        aebuf[(size_t)(s0 + i) * HH + 0] = a0;
        aebuf[(size_t)(s0 + i) * HH + 1] = a1;
        aebuf[(size_t)(s0 + i) * HH + 2] = a2;
        if (attn) attn[eorig[s0 + i]] = fmaxf(fmaxf(a0, a1), a2);
    }
}

// ---------------------------------------------------------------- GAT gather + fused epilogue
// wave-per-node; lane = feature d. acc_h = sum_e alpha_h * z[src][h*DH+d];
// x[n][d] = maybe_relu(max_h(acc_h + bg[h*DH+d])). Atomic-free.
template <int DH>
__global__ __launch_bounds__(256) void gat_gather(const int* __restrict__ rowstart,
                                                  const int* __restrict__ cnt,
                                                  const int* __restrict__ esrc,
                                                  const float* __restrict__ aebuf,
                                                  const float* __restrict__ z,
                                                  const float* __restrict__ bg,
                                                  float* __restrict__ x, int do_relu) {
    constexpr int CO = HH * DH;
    int n = blockIdx.x * 4 + (threadIdx.x >> 6);
    if (n >= NN) return;
    const int lane = threadIdx.x & 63;
    const int s0 = rowstart[n];
    const int deg = cnt[n];
    float a0 = 0.f, a1 = 0.f, a2 = 0.f;
    for (int i = 0; i < deg; ++i) {
        int s = esrc[s0 + i];
        float w0 = aebuf[(size_t)(s0 + i) * HH + 0];
        float w1 = aebuf[(size_t)(s0 + i) * HH + 1];
        float w2 = aebuf[(size_t)(s0 + i) * HH + 2];
        const float* zr = z + (size_t)s * CO;
        if (lane < DH) {
            a0 += w0 * zr[lane];
            a1 += w1 * zr[DH + lane];
            a2 += w2 * zr[2 * DH + lane];
        }
    }
    if (lane < DH) {
        float m = fmaxf(fmaxf(a0 + bg[lane], a1 + bg[DH + lane]), a2 + bg[2 * DH + lane]);
        if (do_relu) m = fmaxf(m, 0.f);
        x[(size_t)n * DH + lane] = m;
    }
}

// ---------------------------------------------------------------- GCN gather (atomic-free)
// agg[n] = rdin[n] * sum_e rdout[src] * x[src]
template <int K>
__global__ __launch_bounds__(256) void gcn_gather(const int* __restrict__ rowstart,
                                                  const int* __restrict__ cnt,
                                                  const int* __restrict__ esrc,
                                                  const float* __restrict__ xin,
                                                  const float* __restrict__ rdout,
                                                  const float* __restrict__ rdin,
                                                  float* __restrict__ agg) {
    int n = blockIdx.x * 4 + (threadIdx.x >> 6);
    if (n >= NN) return;
    const int lane = threadIdx.x & 63;
    const int s0 = rowstart[n];
    const int deg = cnt[n];
    float acc0 = 0.f, acc1 = 0.f;
    for (int i = 0; i < deg; ++i) {
        int s = esrc[s0 + i];
        float sc = rdout[s];
        const float* xr = xin + (size_t)s * K;
        if (lane < K) acc0 += sc * xr[lane];
        if (K > 64 && lane + 64 < K) acc1 += sc * xr[lane + 64];
    }
    const float ri = rdin[n];
    if (lane < K) agg[(size_t)n * K + lane] = acc0 * ri;
    if (K > 64 && lane + 64 < K) agg[(size_t)n * K + lane + 64] = acc1 * ri;
}

// out = relu( in @ W + b ),  (N x K) @ (K x 96); rdin scaling already in `in`.
template <int K>
__global__ __launch_bounds__(192) void gcn_gemm(const float* __restrict__ in,
                                                const float* __restrict__ W,
                                                const float* __restrict__ bias,
                                                float* __restrict__ out) {
    __shared__ float Wl[K * HD];
    __shared__ float hs[RROWS * K];
    __shared__ float bl[HD];
    const int tid = threadIdx.x;
    for (int i = tid; i < K * HD; i += 192) Wl[i] = W[i];
    if (tid < HD) bl[tid] = bias[tid];
    const int base = blockIdx.x * RROWS;
    const int nrow = min(RROWS, NN - base);
    for (int i = tid; i < nrow * K; i += 192) hs[i] = in[(size_t)base * K + i];
    __syncthreads();
    const int co = tid % HD;
    const int grp = tid / HD;  // 0..1, each handles 8 rows
    float acc[8];
#pragma unroll
    for (int j = 0; j < 8; ++j) acc[j] = bl[co];
#pragma unroll 4
    for (int k = 0; k < K; ++k) {
        float w = Wl[k * HD + co];
#pragma unroll
        for (int j = 0; j < 8; ++j) acc[j] += hs[(grp * 8 + j) * K + k] * w;
    }
#pragma unroll
    for (int j = 0; j < 8; ++j) {
        int r = grp * 8 + j;
        if (r < nrow) out[(size_t)(base + r) * HD + co] = fmaxf(acc[j], 0.f);
    }
}

// ---------------------------------------------------------------- pooling + heads
__global__ void pool_k(const float* __restrict__ x, const int* __restrict__ gid,
                       float* __restrict__ s, float* __restrict__ c) {
    int idx = blockIdx.x * blockDim.x + threadIdx.x;
    if (idx >= NN * HD) return;
    int n = idx / HD, f = idx - n * HD;
    int g = gid[n];
    unsafeAtomicAdd(&s[g * HD + f], x[idx]);
    if (f == 0) unsafeAtomicAdd(&c[g], 1.f);
}

__global__ void weight_k(const float* __restrict__ x3, float* __restrict__ w) {
    int n = blockIdx.x * blockDim.x + threadIdx.x;
    if (n >= NN) return;
    w[n] = x3[(size_t)n * HD + 78];
}

__global__ __launch_bounds__(96) void final_k(
    const float* __restrict__ s1, const float* __restrict__ s2, const float* __restrict__ s3,
    const float* __restrict__ c1, const float* __restrict__ c2, const float* __restrict__ c3,
    const float* __restrict__ Wr1, const float* __restrict__ br1,
    const float* __restrict__ Wr2, const float* __restrict__ br2,
    const float* __restrict__ Wcl, const float* __restrict__ bcl,
    float* __restrict__ r1, float* __restrict__ r2, float* __restrict__ cls,
    float* __restrict__ hg3) {
    __shared__ float sh[HD];
    int g = blockIdx.x, f = threadIdx.x;
    float h1v = s1[g * HD + f] / fmaxf(c1[g], 1.f);
    float h2v = s2[g * HD + f] / fmaxf(c2[g], 1.f);
    float h3v = s3[g * HD + f] / fmaxf(c3[g], 1.f);
    hg3[g * HD + f] = h3v;
    sh[f] = h1v * Wr1[f];
    __syncthreads();
    if (f == 0) {
        float t = 0.f;
        for (int i = 0; i < HD; ++i) t += sh[i];
        r1[g] = t + br1[0];
    }
    __syncthreads();
    sh[f] = h2v * Wr2[f];
    __syncthreads();
    if (f == 0) {
        float t = 0.f;
        for (int i = 0; i < HD; ++i) t += sh[i];
        r2[g] = t + br2[0];
    }
    __syncthreads();
    for (int c = 0; c < 10; ++c) {
        sh[f] = h3v * Wcl[f * 10 + c];
        __syncthreads();
        if (f == 0) {
            float t = 0.f;
            for (int i = 0; i < HD; ++i) t += sh[i];
            cls[g * 10 + c] = t + bcl[c];
        }
        __syncthreads();
    }
}

// ---------------------------------------------------------------- host side

struct WS {
    float *z, *xbuf, *ybuf, *el, *er, *aebuf, *rdout, *rdin;
    int *cin, *cout, *rowstart, *cursor, *esrc, *eorig;
};

template <int DH>
static void run_graph(const float* h, const int* src, const int* dst, const int* gid,
                      const float* Wg, const float* al, const float* ar, const float* bg,
                      const float* Wf, const float* bf, const float* W2, const float* b2,
                      int relu_epi, float* attn, float* pool_s, float* pool_c,
                      const WS& w, hipStream_t st) {
    const int nb = (NN + RROWS - 1) / RROWS;
    const int eb = (NE + 255) / 256;
    const int nb256 = (NN + 255) / 256;
    const int wb = (NN + 3) / 4;  // wave-per-node blocks

    gat_nodes<DH, DH><<<nb, 192, 0, st>>>(h, Wg, al, ar, w.z, w.el, w.er);

    // CSR build (dst-sorted) + degrees
    hipMemsetAsync(w.cin, 0, NN * sizeof(int), st);
    hipMemsetAsync(w.cout, 0, NN * sizeof(int), st);
    hist_k<<<eb, 256, 0, st>>>(src, dst, w.cin, w.cout);
    scan_k<<<1, 1024, 0, st>>>(w.cin, w.rowstart, w.cursor);
    fill_k<<<eb, 256, 0, st>>>(src, dst, w.cursor, w.esrc, w.eorig);
    rsqrt_k<<<nb256, 256, 0, st>>>(w.cin, w.cout, w.rdin, w.rdout);

    gat_softmax<<<nb256, 256, 0, st>>>(w.rowstart, w.cin, w.esrc, w.eorig,
                                       w.el, w.er, w.aebuf, attn);
    gat_gather<DH><<<wb, 256, 0, st>>>(w.rowstart, w.cin, w.esrc, w.aebuf, w.z,
                                       bg, w.xbuf, relu_epi);

    // GCN layer 1: xbuf (width DH) -> ybuf (width DH, rdin-scaled) -> xbuf (96)
    gcn_gather<DH><<<wb, 256, 0, st>>>(w.rowstart, w.cin, w.esrc, w.xbuf,
                                       w.rdout, w.rdin, w.ybuf);
    gcn_gemm<DH><<<nb, 192, 0, st>>>(w.ybuf, Wf, bf, w.xbuf);
    // GCN layer 2: xbuf (96) -> ybuf (96) -> xbuf (96)
    gcn_gather<HD><<<wb, 256, 0, st>>>(w.rowstart, w.cin, w.esrc, w.xbuf,
                                       w.rdout, w.rdin, w.ybuf);
    gcn_gemm<HD><<<nb, 192, 0, st>>>(w.ybuf, W2, b2, w.xbuf);

    hipMemsetAsync(pool_s, 0, NG * HD * sizeof(float), st);
    hipMemsetAsync(pool_c, 0, NG * sizeof(float), st);
    pool_k<<<(NN * HD + 255) / 256, 256, 0, st>>>(w.xbuf, gid, pool_s, pool_c);
}

extern "C" void kernel_launch(void* const* d_in, const int* in_sizes, int n_in,
                              void* d_out, int out_size, void* d_ws, size_t ws_size,
                              hipStream_t stream) {
    (void)in_sizes; (void)n_in; (void)out_size; (void)ws_size;
    const float* h1 = (const float*)d_in[0];
    const float* h2 = (const float*)d_in[1];
    const float* h3 = (const float*)d_in[2];
    const int* src1 = (const int*)d_in[3];
    const int* dst1 = (const int*)d_in[4];
    const int* gid1 = (const int*)d_in[5];
    const int* src2 = (const int*)d_in[6];
    const int* dst2 = (const int*)d_in[7];
    const int* gid2 = (const int*)d_in[8];
    const int* src3 = (const int*)d_in[9];
    const int* dst3 = (const int*)d_in[10];
    const int* gid3 = (const int*)d_in[11];
    const float* Wg1 = (const float*)d_in[12];
    const float* al1 = (const float*)d_in[13];
    const float* ar1 = (const float*)d_in[14];
    const float* bg1 = (const float*)d_in[15];
    const float* Wg2 = (const float*)d_in[16];
    const float* al2 = (const float*)d_in[17];
    const float* ar2 = (const float*)d_in[18];
    const float* bg2 = (const float*)d_in[19];
    const float* Wc1 = (const float*)d_in[20];
    const float* bc1 = (const float*)d_in[21];
    const float* Wc2 = (const float*)d_in[22];
    const float* bc2 = (const float*)d_in[23];
    const float* Wc3 = (const float*)d_in[24];
    const float* bc3 = (const float*)d_in[25];
    const float* Wr1 = (const float*)d_in[26];
    const float* br1 = (const float*)d_in[27];
    const float* Wr2 = (const float*)d_in[28];
    const float* br2 = (const float*)d_in[29];
    const float* Wcl = (const float*)d_in[30];
    const float* bcl = (const float*)d_in[31];

    float* out = (float*)d_out;
    float* o_r1 = out + 0;
    float* o_r2 = out + 100;
    float* o_cls = out + 200;
    float* o_attn1 = out + 1200;
    float* o_attn3 = out + 401200;
    float* o_weight = out + 801200;
    float* o_hg3 = out + 841200;

    // workspace layout
    float* ws = (float*)d_ws;
    size_t off = 0;
    WS w;
    w.z = ws + off;     off += (size_t)NN * 192;
    w.xbuf = ws + off;  off += (size_t)NN * HD;
    w.ybuf = ws + off;  off += (size_t)NN * HD;
    w.el = ws + off;    off += (size_t)NN * HH;
    w.er = ws + off;    off += (size_t)NN * HH;
    w.aebuf = ws + off; off += (size_t)NE * HH;
    w.rdout = ws + off; off += NN;
    w.rdin = ws + off;  off += NN;
    float* s1 = ws + off; off += NG * HD;
    float* s2 = ws + off; off += NG * HD;
    float* s3 = ws + off; off += NG * HD;
    float* c1 = ws + off; off += NG;
    float* c2 = ws + off; off += NG;
    float* c3 = ws + off; off += NG;
    w.cin = (int*)(ws + off);      off += NN;
    w.cout = (int*)(ws + off);     off += NN;
    w.rowstart = (int*)(ws + off); off += NN;
    w.cursor = (int*)(ws + off);   off += NN;
    w.esrc = (int*)(ws + off);     off += NE;
    w.eorig = (int*)(ws + off);    off += NE;

    // graph 1: GAT(Wg1, Dh=63) -> relu(max) -> GCN(Wc3) -> GCN(Wc2), attn out
    run_graph<63>(h1, src1, dst1, gid1, Wg1, al1, ar1, bg1, Wc3, bc3, Wc2, bc2,
                  1, o_attn1, s1, c1, w, stream);
    // graph 2: same GAT weights, no relu on max, no attn out
    run_graph<63>(h2, src2, dst2, gid2, Wg1, al1, ar1, bg1, Wc3, bc3, Wc2, bc2,
                  0, nullptr, s2, c2, w, stream);
    // graph 3: GAT(Wg2, Dh=64), no relu on max, attn out; GCN(Wc1) then GCN(Wc2)
    run_graph<64>(h3, src3, dst3, gid3, Wg2, al2, ar2, bg2, Wc1, bc1, Wc2, bc2,
                  0, o_attn3, s3, c3, w, stream);

    weight_k<<<(NN + 255) / 256, 256, 0, stream>>>(w.xbuf, o_weight);
    final_k<<<NG, 96, 0, stream>>>(s1, s2, s3, c1, c2, c3, Wr1, br1, Wr2, br2,
                                   Wcl, bcl, o_r1, o_r2, o_cls, o_hg3);
}

// Round 6
// 1833.940 us; speedup vs baseline: 2.4059x; 1.3090x over previous
//
#include <hip/hip_runtime.h>

#define NN 40000
#define NE 400000
#define NG 100
#define HH 3
#define HD 96

static constexpr int RROWS = 16;  // rows per block in node GEMMs
static constexpr int PBLK = 128;  // nodes per block in pool_k

// ---------------------------------------------------------------- utilities

__device__ __forceinline__ float wsum(float v) {
#pragma unroll
    for (int m = 32; m >= 1; m >>= 1) v += __shfl_xor(v, m);
    return v;
}

// ---------------------------------------------------------------- GAT node GEMM
// z = h @ Wg  (N x DIN) @ (DIN x 3*DH), plus el/er head-wise dots with al/ar.
template <int DIN, int DH>
__global__ __launch_bounds__(192) void gat_nodes(const float* __restrict__ h,
                                                 const float* __restrict__ W,
                                                 const float* __restrict__ al,
                                                 const float* __restrict__ ar,
                                                 float* __restrict__ z,
                                                 float* __restrict__ el,
                                                 float* __restrict__ er) {
    constexpr int CO = HH * DH;
    __shared__ float Wl[DIN * CO];
    __shared__ float alS[CO], arS[CO];
    __shared__ float hs[RROWS * DIN];
    const int tid = threadIdx.x;
    for (int i = tid; i < DIN * CO; i += 192) Wl[i] = W[i];
    for (int i = tid; i < CO; i += 192) { alS[i] = al[i]; arS[i] = ar[i]; }
    const int base = blockIdx.x * RROWS;
    const int nrow = min(RROWS, NN - base);
    for (int i = tid; i < nrow * DIN; i += 192) hs[i] = h[(size_t)base * DIN + i];
    __syncthreads();
    const int head = tid >> 6, d = tid & 63;
    const bool valid = d < DH;
    const int col = head * DH + d;
    for (int r = 0; r < nrow; ++r) {
        float acc = 0.f;
        if (valid) {
#pragma unroll 4
            for (int k = 0; k < DIN; ++k) acc += hs[r * DIN + k] * Wl[k * CO + col];
        }
        const int row = base + r;
        if (valid) z[(size_t)row * CO + col] = acc;
        float cl = valid ? acc * alS[col] : 0.f;
        float cr = valid ? acc * arS[col] : 0.f;
        cl = wsum(cl);
        cr = wsum(cr);
        if (d == 0) {
            el[row * HH + head] = cl;
            er[row * HH + head] = cr;
        }
    }
}

// ---------------------------------------------------------------- CSR build
__global__ void hist_k(const int* __restrict__ src, const int* __restrict__ dst,
                       int* __restrict__ cin, int* __restrict__ cout) {
    int e = blockIdx.x * blockDim.x + threadIdx.x;
    if (e >= NE) return;
    atomicAdd(&cin[dst[e]], 1);
    atomicAdd(&cout[src[e]], 1);
}

// single-block exclusive scan of cin -> rowstart (+ cursor copy)
__global__ __launch_bounds__(1024) void scan_k(const int* __restrict__ cin,
                                               int* __restrict__ rowstart,
                                               int* __restrict__ cursor) {
    __shared__ int part[1024];
    const int t = threadIdx.x;
    const int lo = t * 40;
    const int hi = min(lo + 40, NN);
    int s = 0;
    for (int i = lo; i < hi; ++i) s += cin[i];
    part[t] = s;
    __syncthreads();
    for (int off = 1; off < 1024; off <<= 1) {
        int u = (t >= off) ? part[t - off] : 0;
        __syncthreads();
        part[t] += u;
        __syncthreads();
    }
    int base = part[t] - s;  // exclusive prefix of this thread's chunk
    for (int i = lo; i < hi; ++i) {
        rowstart[i] = base;
        cursor[i] = base;
        base += cin[i];
    }
}

__global__ void fill_k(const int* __restrict__ src, const int* __restrict__ dst,
                       int* __restrict__ cursor, int* __restrict__ esrc,
                       int* __restrict__ eorig) {
    int e = blockIdx.x * blockDim.x + threadIdx.x;
    if (e >= NE) return;
    int pos = atomicAdd(&cursor[dst[e]], 1);
    esrc[pos] = src[e];
    eorig[pos] = e;
}

__global__ void rsqrt_k(const int* __restrict__ cin, const int* __restrict__ cout,
                        float* __restrict__ rdin, float* __restrict__ rdout) {
    int n = blockIdx.x * blockDim.x + threadIdx.x;
    if (n >= NN) return;
    rdin[n] = 1.f / sqrtf((float)max(cin[n], 1));
    rdout[n] = 1.f / sqrtf((float)max(cout[n], 1));
}

// ---------------------------------------------------------------- GAT softmax (per dst node, serial over CSR row)
__global__ void gat_softmax(const int* __restrict__ rowstart, const int* __restrict__ cnt,
                            const int* __restrict__ esrc, const int* __restrict__ eorig,
                            const float* __restrict__ el, const float* __restrict__ er,
                            float* __restrict__ aebuf, float* __restrict__ attn) {
    int n = blockIdx.x * blockDim.x + threadIdx.x;
    if (n >= NN) return;
    const int s0 = rowstart[n];
    const int deg = cnt[n];
    if (deg == 0) return;
    const float er0 = er[n * HH + 0], er1 = er[n * HH + 1], er2 = er[n * HH + 2];
    float m0 = -3.4e38f, m1 = -3.4e38f, m2 = -3.4e38f;
    for (int i = 0; i < deg; ++i) {
        int s = esrc[s0 + i];
        float v0 = el[s * HH + 0] + er0;
        float v1 = el[s * HH + 1] + er1;
        float v2 = el[s * HH + 2] + er2;
        v0 = v0 > 0.f ? v0 : 0.2f * v0;
        v1 = v1 > 0.f ? v1 : 0.2f * v1;
        v2 = v2 > 0.f ? v2 : 0.2f * v2;
        aebuf[(size_t)(s0 + i) * HH + 0] = v0;
        aebuf[(size_t)(s0 + i) * HH + 1] = v1;
        aebuf[(size_t)(s0 + i) * HH + 2] = v2;
        m0 = fmaxf(m0, v0); m1 = fmaxf(m1, v1); m2 = fmaxf(m2, v2);
    }
    float d0 = 0.f, d1 = 0.f, d2 = 0.f;
    for (int i = 0; i < deg; ++i) {
        float p0 = expf(aebuf[(size_t)(s0 + i) * HH + 0] - m0);
        float p1 = expf(aebuf[(size_t)(s0 + i) * HH + 1] - m1);
        float p2 = expf(aebuf[(size_t)(s0 + i) * HH + 2] - m2);
        aebuf[(size_t)(s0 + i) * HH + 0] = p0;
        aebuf[(size_t)(s0 + i) * HH + 1] = p1;
        aebuf[(size_t)(s0 + i) * HH + 2] = p2;
        d0 += p0; d1 += p1; d2 += p2;
    }
    const float i0 = 1.f / d0, i1 = 1.f / d1, i2 = 1.f / d2;
    for (int i = 0; i < deg; ++i) {
        float a0 = aebuf[(size_t)(s0 + i) * HH + 0] * i0;
        float a1 = aebuf[(size_t)(s0 + i) * HH + 1] * i1;
        float a2 = aebuf[(size_t)(s0 + i) * HH + 2] * i2;
        aebuf[(size_t)(s0 + i) * HH + 0] = a0;
        aebuf[(size_t)(s0 + i) * HH + 1] = a1;
        aebuf[(size_t)(s0 + i) * HH + 2] = a2;
        if (attn) attn[eorig[s0 + i]] = fmaxf(fmaxf(a0, a1), a2);
    }
}

// ---------------------------------------------------------------- GAT gather + fused epilogue
// wave-per-node; lane = feature d. acc_h = sum_e alpha_h * z[src][h*DH+d];
// x[n][d] = maybe_relu(max_h(acc_h + bg[h*DH+d])). Atomic-free.
template <int DH>
__global__ __launch_bounds__(256) void gat_gather(const int* __restrict__ rowstart,
                                                  const int* __restrict__ cnt,
                                                  const int* __restrict__ esrc,
                                                  const float* __restrict__ aebuf,
                                                  const float* __restrict__ z,
                                                  const float* __restrict__ bg,
                                                  float* __restrict__ x, int do_relu) {
    constexpr int CO = HH * DH;
    int n = blockIdx.x * 4 + (threadIdx.x >> 6);
    if (n >= NN) return;
    const int lane = threadIdx.x & 63;
    const int s0 = rowstart[n];
    const int deg = cnt[n];
    float a0 = 0.f, a1 = 0.f, a2 = 0.f;
    for (int i = 0; i < deg; ++i) {
        int s = esrc[s0 + i];
        float w0 = aebuf[(size_t)(s0 + i) * HH + 0];
        float w1 = aebuf[(size_t)(s0 + i) * HH + 1];
        float w2 = aebuf[(size_t)(s0 + i) * HH + 2];
        const float* zr = z + (size_t)s * CO;
        if (lane < DH) {
            a0 += w0 * zr[lane];
            a1 += w1 * zr[DH + lane];
            a2 += w2 * zr[2 * DH + lane];
        }
    }
    if (lane < DH) {
        float m = fmaxf(fmaxf(a0 + bg[lane], a1 + bg[DH + lane]), a2 + bg[2 * DH + lane]);
        if (do_relu) m = fmaxf(m, 0.f);
        x[(size_t)n * DH + lane] = m;
    }
}

// ---------------------------------------------------------------- GCN gather (atomic-free)
// agg[n] = rdin[n] * sum_e rdout[src] * x[src]
template <int K>
__global__ __launch_bounds__(256) void gcn_gather(const int* __restrict__ rowstart,
                                                  const int* __restrict__ cnt,
                                                  const int* __restrict__ esrc,
                                                  const float* __restrict__ xin,
                                                  const float* __restrict__ rdout,
                                                  const float* __restrict__ rdin,
                                                  float* __restrict__ agg) {
    int n = blockIdx.x * 4 + (threadIdx.x >> 6);
    if (n >= NN) return;
    const int lane = threadIdx.x & 63;
    const int s0 = rowstart[n];
    const int deg = cnt[n];
    float acc0 = 0.f, acc1 = 0.f;
    for (int i = 0; i < deg; ++i) {
        int s = esrc[s0 + i];
        float sc = rdout[s];
        const float* xr = xin + (size_t)s * K;
        if (lane < K) acc0 += sc * xr[lane];
        if (K > 64 && lane + 64 < K) acc1 += sc * xr[lane + 64];
    }
    const float ri = rdin[n];
    if (lane < K) agg[(size_t)n * K + lane] = acc0 * ri;
    if (K > 64 && lane + 64 < K) agg[(size_t)n * K + lane + 64] = acc1 * ri;
}

// out = relu( in @ W + b ),  (N x K) @ (K x 96); rdin scaling already in `in`.
template <int K>
__global__ __launch_bounds__(192) void gcn_gemm(const float* __restrict__ in,
                                                const float* __restrict__ W,
                                                const float* __restrict__ bias,
                                                float* __restrict__ out) {
    __shared__ float Wl[K * HD];
    __shared__ float hs[RROWS * K];
    __shared__ float bl[HD];
    const int tid = threadIdx.x;
    for (int i = tid; i < K * HD; i += 192) Wl[i] = W[i];
    if (tid < HD) bl[tid] = bias[tid];
    const int base = blockIdx.x * RROWS;
    const int nrow = min(RROWS, NN - base);
    for (int i = tid; i < nrow * K; i += 192) hs[i] = in[(size_t)base * K + i];
    __syncthreads();
    const int co = tid % HD;
    const int grp = tid / HD;  // 0..1, each handles 8 rows
    float acc[8];
#pragma unroll
    for (int j = 0; j < 8; ++j) acc[j] = bl[co];
#pragma unroll 4
    for (int k = 0; k < K; ++k) {
        float w = Wl[k * HD + co];
#pragma unroll
        for (int j = 0; j < 8; ++j) acc[j] += hs[(grp * 8 + j) * K + k] * w;
    }
#pragma unroll
    for (int j = 0; j < 8; ++j) {
        int r = grp * 8 + j;
        if (r < nrow) out[(size_t)(base + r) * HD + co] = fmaxf(acc[j], 0.f);
    }
}

// ---------------------------------------------------------------- pooling + heads
// One block per PBLK contiguous nodes; 96 threads = one per feature column.
// gid is sorted, so each block spans ~1-2 group runs: accumulate in register,
// flush one atomicAdd per (run, feature). Correct (just slower) if unsorted.
// Replaces the 3.84M-atomic version that was contention-bound at 249 us
// (round-4 counters: 100 GB/s, VALUBusy 0.6%).
__global__ __launch_bounds__(96) void pool_k(const float* __restrict__ x,
                                             const int* __restrict__ gid,
                                             float* __restrict__ s,
                                             float* __restrict__ c) {
    const int f = threadIdx.x;  // 0..95
    const int n0 = blockIdx.x * PBLK;
    const int n1 = min(n0 + PBLK, NN);
    int cur = gid[n0];
    float acc = 0.f;
    int cnt = 0;
    for (int n = n0; n < n1; ++n) {
        int g = gid[n];  // wave-uniform
        if (g != cur) {
            unsafeAtomicAdd(&s[cur * HD + f], acc);
            if (f == 0) unsafeAtomicAdd(&c[cur], (float)cnt);
            acc = 0.f;
            cnt = 0;
            cur = g;
        }
        acc += x[(size_t)n * HD + f];
        ++cnt;
    }
    unsafeAtomicAdd(&s[cur * HD + f], acc);
    if (f == 0) unsafeAtomicAdd(&c[cur], (float)cnt);
}

__global__ void weight_k(const float* __restrict__ x3, float* __restrict__ w) {
    int n = blockIdx.x * blockDim.x + threadIdx.x;
    if (n >= NN) return;
    w[n] = x3[(size_t)n * HD + 78];
}

__global__ __launch_bounds__(96) void final_k(
    const float* __restrict__ s1, const float* __restrict__ s2, const float* __restrict__ s3,
    const float* __restrict__ c1, const float* __restrict__ c2, const float* __restrict__ c3,
    const float* __restrict__ Wr1, const float* __restrict__ br1,
    const float* __restrict__ Wr2, const float* __restrict__ br2,
    const float* __restrict__ Wcl, const float* __restrict__ bcl,
    float* __restrict__ r1, float* __restrict__ r2, float* __restrict__ cls,
    float* __restrict__ hg3) {
    __shared__ float sh[HD];
    int g = blockIdx.x, f = threadIdx.x;
    float h1v = s1[g * HD + f] / fmaxf(c1[g], 1.f);
    float h2v = s2[g * HD + f] / fmaxf(c2[g], 1.f);
    float h3v = s3[g * HD + f] / fmaxf(c3[g], 1.f);
    hg3[g * HD + f] = h3v;
    sh[f] = h1v * Wr1[f];
    __syncthreads();
    if (f == 0) {
        float t = 0.f;
        for (int i = 0; i < HD; ++i) t += sh[i];
        r1[g] = t + br1[0];
    }
    __syncthreads();
    sh[f] = h2v * Wr2[f];
    __syncthreads();
    if (f == 0) {
        float t = 0.f;
        for (int i = 0; i < HD; ++i) t += sh[i];
        r2[g] = t + br2[0];
    }
    __syncthreads();
    for (int c = 0; c < 10; ++c) {
        sh[f] = h3v * Wcl[f * 10 + c];
        __syncthreads();
        if (f == 0) {
            float t = 0.f;
            for (int i = 0; i < HD; ++i) t += sh[i];
            cls[g * 10 + c] = t + bcl[c];
        }
        __syncthreads();
    }
}

// ---------------------------------------------------------------- host side

struct WS {
    float *z, *xbuf, *ybuf, *el, *er, *aebuf, *rdout, *rdin;
    int *cin, *cout, *rowstart, *cursor, *esrc, *eorig;
};

template <int DH>
static void run_graph(const float* h, const int* src, const int* dst, const int* gid,
                      const float* Wg, const float* al, const float* ar, const float* bg,
                      const float* Wf, const float* bf, const float* W2, const float* b2,
                      int relu_epi, float* attn, float* pool_s, float* pool_c,
                      const WS& w, hipStream_t st) {
    const int nb = (NN + RROWS - 1) / RROWS;
    const int eb = (NE + 255) / 256;
    const int nb256 = (NN + 255) / 256;
    const int wb = (NN + 3) / 4;  // wave-per-node blocks

    gat_nodes<DH, DH><<<nb, 192, 0, st>>>(h, Wg, al, ar, w.z, w.el, w.er);

    // CSR build (dst-sorted) + degrees
    hipMemsetAsync(w.cin, 0, NN * sizeof(int), st);
    hipMemsetAsync(w.cout, 0, NN * sizeof(int), st);
    hist_k<<<eb, 256, 0, st>>>(src, dst, w.cin, w.cout);
    scan_k<<<1, 1024, 0, st>>>(w.cin, w.rowstart, w.cursor);
    fill_k<<<eb, 256, 0, st>>>(src, dst, w.cursor, w.esrc, w.eorig);
    rsqrt_k<<<nb256, 256, 0, st>>>(w.cin, w.cout, w.rdin, w.rdout);

    gat_softmax<<<nb256, 256, 0, st>>>(w.rowstart, w.cin, w.esrc, w.eorig,
                                       w.el, w.er, w.aebuf, attn);
    gat_gather<DH><<<wb, 256, 0, st>>>(w.rowstart, w.cin, w.esrc, w.aebuf, w.z,
                                       bg, w.xbuf, relu_epi);

    // GCN layer 1: xbuf (width DH) -> ybuf (width DH, rdin-scaled) -> xbuf (96)
    gcn_gather<DH><<<wb, 256, 0, st>>>(w.rowstart, w.cin, w.esrc, w.xbuf,
                                       w.rdout, w.rdin, w.ybuf);
    gcn_gemm<DH><<<nb, 192, 0, st>>>(w.ybuf, Wf, bf, w.xbuf);
    // GCN layer 2: xbuf (96) -> ybuf (96) -> xbuf (96)
    gcn_gather<HD><<<wb, 256, 0, st>>>(w.rowstart, w.cin, w.esrc, w.xbuf,
                                       w.rdout, w.rdin, w.ybuf);
    gcn_gemm<HD><<<nb, 192, 0, st>>>(w.ybuf, W2, b2, w.xbuf);

    hipMemsetAsync(pool_s, 0, NG * HD * sizeof(float), st);
    hipMemsetAsync(pool_c, 0, NG * sizeof(float), st);
    pool_k<<<(NN + PBLK - 1) / PBLK, 96, 0, st>>>(w.xbuf, gid, pool_s, pool_c);
}

extern "C" void kernel_launch(void* const* d_in, const int* in_sizes, int n_in,
                              void* d_out, int out_size, void* d_ws, size_t ws_size,
                              hipStream_t stream) {
    (void)in_sizes; (void)n_in; (void)out_size; (void)ws_size;
    const float* h1 = (const float*)d_in[0];
    const float* h2 = (const float*)d_in[1];
    const float* h3 = (const float*)d_in[2];
    const int* src1 = (const int*)d_in[3];
    const int* dst1 = (const int*)d_in[4];
    const int* gid1 = (const int*)d_in[5];
    const int* src2 = (const int*)d_in[6];
    const int* dst2 = (const int*)d_in[7];
    const int* gid2 = (const int*)d_in[8];
    const int* src3 = (const int*)d_in[9];
    const int* dst3 = (const int*)d_in[10];
    const int* gid3 = (const int*)d_in[11];
    const float* Wg1 = (const float*)d_in[12];
    const float* al1 = (const float*)d_in[13];
    const float* ar1 = (const float*)d_in[14];
    const float* bg1 = (const float*)d_in[15];
    const float* Wg2 = (const float*)d_in[16];
    const float* al2 = (const float*)d_in[17];
    const float* ar2 = (const float*)d_in[18];
    const float* bg2 = (const float*)d_in[19];
    const float* Wc1 = (const float*)d_in[20];
    const float* bc1 = (const float*)d_in[21];
    const float* Wc2 = (const float*)d_in[22];
    const float* bc2 = (const float*)d_in[23];
    const float* Wc3 = (const float*)d_in[24];
    const float* bc3 = (const float*)d_in[25];
    const float* Wr1 = (const float*)d_in[26];
    const float* br1 = (const float*)d_in[27];
    const float* Wr2 = (const float*)d_in[28];
    const float* br2 = (const float*)d_in[29];
    const float* Wcl = (const float*)d_in[30];
    const float* bcl = (const float*)d_in[31];

    float* out = (float*)d_out;
    float* o_r1 = out + 0;
    float* o_r2 = out + 100;
    float* o_cls = out + 200;
    float* o_attn1 = out + 1200;
    float* o_attn3 = out + 401200;
    float* o_weight = out + 801200;
    float* o_hg3 = out + 841200;

    // workspace layout
    float* ws = (float*)d_ws;
    size_t off = 0;
    WS w;
    w.z = ws + off;     off += (size_t)NN * 192;
    w.xbuf = ws + off;  off += (size_t)NN * HD;
    w.ybuf = ws + off;  off += (size_t)NN * HD;
    w.el = ws + off;    off += (size_t)NN * HH;
    w.er = ws + off;    off += (size_t)NN * HH;
    w.aebuf = ws + off; off += (size_t)NE * HH;
    w.rdout = ws + off; off += NN;
    w.rdin = ws + off;  off += NN;
    float* s1 = ws + off; off += NG * HD;
    float* s2 = ws + off; off += NG * HD;
    float* s3 = ws + off; off += NG * HD;
    float* c1 = ws + off; off += NG;
    float* c2 = ws + off; off += NG;
    float* c3 = ws + off; off += NG;
    w.cin = (int*)(ws + off);      off += NN;
    w.cout = (int*)(ws + off);     off += NN;
    w.rowstart = (int*)(ws + off); off += NN;
    w.cursor = (int*)(ws + off);   off += NN;
    w.esrc = (int*)(ws + off);     off += NE;
    w.eorig = (int*)(ws + off);    off += NE;

    // graph 1: GAT(Wg1, Dh=63) -> relu(max) -> GCN(Wc3) -> GCN(Wc2), attn out
    run_graph<63>(h1, src1, dst1, gid1, Wg1, al1, ar1, bg1, Wc3, bc3, Wc2, bc2,
                  1, o_attn1, s1, c1, w, stream);
    // graph 2: same GAT weights, no relu on max, no attn out
    run_graph<63>(h2, src2, dst2, gid2, Wg1, al1, ar1, bg1, Wc3, bc3, Wc2, bc2,
                  0, nullptr, s2, c2, w, stream);
    // graph 3: GAT(Wg2, Dh=64), no relu on max, attn out; GCN(Wc1) then GCN(Wc2)
    run_graph<64>(h3, src3, dst3, gid3, Wg2, al2, ar2, bg2, Wc1, bc1, Wc2, bc2,
                  0, o_attn3, s3, c3, w, stream);

    weight_k<<<(NN + 255) / 256, 256, 0, stream>>>(w.xbuf, o_weight);
    final_k<<<NG, 96, 0, stream>>>(s1, s2, s3, c1, c2, c3, Wr1, br1, Wr2, br2,
                                   Wcl, bcl, o_r1, o_r2, o_cls, o_hg3);
}

// Round 7
// 1657.268 us; speedup vs baseline: 2.6624x; 1.1066x over previous
//
#include <hip/hip_runtime.h>

#define NN 40000
#define NE 400000
#define NG 100
#define HH 3
#define HD 96

static constexpr int RROWS = 16;  // rows per block in node GEMMs
static constexpr int PBLK = 128;  // nodes per block in pool_k

// ---------------------------------------------------------------- GAT z GEMM (register-tiled)
// z = h @ Wg  (N x DIN) @ (DIN x 3*DH). Block = 64 rows x 192 cols, 192 threads,
// each thread an 8x8 register tile (cols interleaved at stride 24).
// Replaces the 1-col-per-thread version (153 us, VALUBusy 21.6%: 2 LDS b32
// reads per FMA). Here: 16 conflict-free b32 reads per 64 FMAs.
template <int DIN, int DH>
__global__ __launch_bounds__(192) void gatz_gemm(const float* __restrict__ h,
                                                 const float* __restrict__ W,
                                                 float* __restrict__ z) {
    constexpr int CO = HH * DH;   // 189 or 192
    constexpr int COP = 192;      // padded col count (= blockDim)
    constexpr int KP = 64;        // padded K
    constexpr int HSTR = 65;      // hsl row stride (65%32=1 -> conflict-free)
    __shared__ float Wl[KP * COP];
    __shared__ float hsl[64 * HSTR];
    const int tid = threadIdx.x;
    // stage W: thread tid owns column tid; zero-pad rows >= DIN and cols >= CO
#pragma unroll 1
    for (int k = 0; k < KP; ++k)
        Wl[k * COP + tid] = (k < DIN && tid < CO) ? W[k * CO + tid] : 0.f;
    // stage h: 64 rows (NN % 64 == 0 -> no row guard), zero-pad k >= DIN
    const int base = blockIdx.x * 64;
#pragma unroll 1
    for (int idx = tid; idx < 64 * KP; idx += 192) {
        int r = idx >> 6, k = idx & 63;
        hsl[r * HSTR + k] = (k < DIN) ? h[(size_t)(base + r) * DIN + k] : 0.f;
    }
    __syncthreads();
    const int rt = tid / 24;  // 0..7 -> rows rt*8..rt*8+7
    const int ct = tid % 24;  // cols ct + 24*j, j=0..7
    const int r0 = rt * 8;
    float acc[8][8];
#pragma unroll
    for (int i = 0; i < 8; ++i)
#pragma unroll
        for (int j = 0; j < 8; ++j) acc[i][j] = 0.f;
#pragma unroll 2
    for (int k = 0; k < KP; ++k) {
        float hv[8], wv[8];
#pragma unroll
        for (int i = 0; i < 8; ++i) hv[i] = hsl[(r0 + i) * HSTR + k];
#pragma unroll
        for (int j = 0; j < 8; ++j) wv[j] = Wl[k * COP + ct + 24 * j];
#pragma unroll
        for (int i = 0; i < 8; ++i)
#pragma unroll
            for (int j = 0; j < 8; ++j) acc[i][j] += hv[i] * wv[j];
    }
#pragma unroll
    for (int i = 0; i < 8; ++i) {
        const size_t row = base + r0 + i;
#pragma unroll
        for (int j = 0; j < 8; ++j) {
            int c = ct + 24 * j;
            if (c < CO) z[row * CO + c] = acc[i][j];
        }
    }
}

// Wal[k][h] = sum_d W[k][h*DH+d]*al[h][d]  (folds el = z@al into h@(W@al))
template <int DIN, int DH>
__global__ __launch_bounds__(192) void waler_k(const float* __restrict__ W,
                                               const float* __restrict__ al,
                                               const float* __restrict__ ar,
                                               float* __restrict__ Wal,
                                               float* __restrict__ War) {
    constexpr int CO = HH * DH;
    const int t = threadIdx.x;
    if (t >= DIN * HH) return;
    const int k = t / HH, hd = t % HH;
    float sl = 0.f, sr = 0.f;
    for (int d = 0; d < DH; ++d) {
        float wv = W[k * CO + hd * DH + d];
        sl += wv * al[hd * DH + d];
        sr += wv * ar[hd * DH + d];
    }
    Wal[k * HH + hd] = sl;
    War[k * HH + hd] = sr;
}

// el[n][h] = h[n] . Wal[:,h] ; er likewise.
template <int DIN>
__global__ __launch_bounds__(128) void el_er_k(const float* __restrict__ h,
                                               const float* __restrict__ Wal,
                                               const float* __restrict__ War,
                                               float* __restrict__ el,
                                               float* __restrict__ er) {
    constexpr int STR = (DIN % 2 == 0) ? DIN + 1 : DIN;  // 63->63, 64->65
    __shared__ float hsl[128 * STR];
    __shared__ float walS[DIN * HH], warS[DIN * HH];
    const int t = threadIdx.x;
    const int base = blockIdx.x * 128;
    const int nrow = min(128, NN - base);
    for (int idx = t; idx < nrow * DIN; idx += 128) {
        int r = idx / DIN, k = idx - r * DIN;
        hsl[r * STR + k] = h[(size_t)base * DIN + idx];
    }
    for (int idx = t; idx < DIN * HH; idx += 128) {
        walS[idx] = Wal[idx];
        warS[idx] = War[idx];
    }
    __syncthreads();
    if (t >= nrow) return;
    float e0 = 0.f, e1 = 0.f, e2 = 0.f, f0 = 0.f, f1 = 0.f, f2 = 0.f;
    for (int k = 0; k < DIN; ++k) {
        float hv = hsl[t * STR + k];
        e0 += hv * walS[k * HH + 0];
        e1 += hv * walS[k * HH + 1];
        e2 += hv * walS[k * HH + 2];
        f0 += hv * warS[k * HH + 0];
        f1 += hv * warS[k * HH + 1];
        f2 += hv * warS[k * HH + 2];
    }
    const int n = base + t;
    el[n * HH + 0] = e0; el[n * HH + 1] = e1; el[n * HH + 2] = e2;
    er[n * HH + 0] = f0; er[n * HH + 1] = f1; er[n * HH + 2] = f2;
}

// ---------------------------------------------------------------- CSR build
__global__ void hist_k(const int* __restrict__ src, const int* __restrict__ dst,
                       int* __restrict__ cin, int* __restrict__ cout) {
    int e = blockIdx.x * blockDim.x + threadIdx.x;
    if (e >= NE) return;
    atomicAdd(&cin[dst[e]], 1);
    atomicAdd(&cout[src[e]], 1);
}

// single-block exclusive scan of cin -> rowstart (+ cursor copy)
__global__ __launch_bounds__(1024) void scan_k(const int* __restrict__ cin,
                                               int* __restrict__ rowstart,
                                               int* __restrict__ cursor) {
    __shared__ int part[1024];
    const int t = threadIdx.x;
    const int lo = t * 40;
    const int hi = min(lo + 40, NN);
    int s = 0;
    for (int i = lo; i < hi; ++i) s += cin[i];
    part[t] = s;
    __syncthreads();
    for (int off = 1; off < 1024; off <<= 1) {
        int u = (t >= off) ? part[t - off] : 0;
        __syncthreads();
        part[t] += u;
        __syncthreads();
    }
    int base = part[t] - s;  // exclusive prefix of this thread's chunk
    for (int i = lo; i < hi; ++i) {
        rowstart[i] = base;
        cursor[i] = base;
        base += cin[i];
    }
}

__global__ void fill_k(const int* __restrict__ src, const int* __restrict__ dst,
                       int* __restrict__ cursor, int* __restrict__ esrc,
                       int* __restrict__ eorig) {
    int e = blockIdx.x * blockDim.x + threadIdx.x;
    if (e >= NE) return;
    int pos = atomicAdd(&cursor[dst[e]], 1);
    esrc[pos] = src[e];
    eorig[pos] = e;
}

__global__ void rsqrt_k(const int* __restrict__ cin, const int* __restrict__ cout,
                        float* __restrict__ rdin, float* __restrict__ rdout) {
    int n = blockIdx.x * blockDim.x + threadIdx.x;
    if (n >= NN) return;
    rdin[n] = 1.f / sqrtf((float)max(cin[n], 1));
    rdout[n] = 1.f / sqrtf((float)max(cout[n], 1));
}

// ---------------------------------------------------------------- GAT softmax (per dst node, serial over CSR row)
__global__ void gat_softmax(const int* __restrict__ rowstart, const int* __restrict__ cnt,
                            const int* __restrict__ esrc, const int* __restrict__ eorig,
                            const float* __restrict__ el, const float* __restrict__ er,
                            float* __restrict__ aebuf, float* __restrict__ attn) {
    int n = blockIdx.x * blockDim.x + threadIdx.x;
    if (n >= NN) return;
    const int s0 = rowstart[n];
    const int deg = cnt[n];
    if (deg == 0) return;
    const float er0 = er[n * HH + 0], er1 = er[n * HH + 1], er2 = er[n * HH + 2];
    float m0 = -3.4e38f, m1 = -3.4e38f, m2 = -3.4e38f;
    for (int i = 0; i < deg; ++i) {
        int s = esrc[s0 + i];
        float v0 = el[s * HH + 0] + er0;
        float v1 = el[s * HH + 1] + er1;
        float v2 = el[s * HH + 2] + er2;
        v0 = v0 > 0.f ? v0 : 0.2f * v0;
        v1 = v1 > 0.f ? v1 : 0.2f * v1;
        v2 = v2 > 0.f ? v2 : 0.2f * v2;
        aebuf[(size_t)(s0 + i) * HH + 0] = v0;
        aebuf[(size_t)(s0 + i) * HH + 1] = v1;
        aebuf[(size_t)(s0 + i) * HH + 2] = v2;
        m0 = fmaxf(m0, v0); m1 = fmaxf(m1, v1); m2 = fmaxf(m2, v2);
    }
    float d0 = 0.f, d1 = 0.f, d2 = 0.f;
    for (int i = 0; i < deg; ++i) {
        float p0 = expf(aebuf[(size_t)(s0 + i) * HH + 0] - m0);
        float p1 = expf(aebuf[(size_t)(s0 + i) * HH + 1] - m1);
        float p2 = expf(aebuf[(size_t)(s0 + i) * HH + 2] - m2);
        aebuf[(size_t)(s0 + i) * HH + 0] = p0;
        aebuf[(size_t)(s0 + i) * HH + 1] = p1;
        aebuf[(size_t)(s0 + i) * HH + 2] = p2;
        d0 += p0; d1 += p1; d2 += p2;
    }
    const float i0 = 1.f / d0, i1 = 1.f / d1, i2 = 1.f / d2;
    for (int i = 0; i < deg; ++i) {
        float a0 = aebuf[(size_t)(s0 + i) * HH + 0] * i0;
        float a1 = aebuf[(size_t)(s0 + i) * HH + 1] * i1;
        float a2 = aebuf[(size_t)(s0 + i) * HH + 2] * i2;
        aebuf[(size_t)(s0 + i) * HH + 0] = a0;
        aebuf[(size_t)(s0 + i) * HH + 1] = a1;
        aebuf[(size_t)(s0 + i) * HH + 2] = a2;
        if (attn) attn[eorig[s0 + i]] = fmaxf(fmaxf(a0, a1), a2);
    }
}

// ---------------------------------------------------------------- GAT gather + fused epilogue
// wave-per-node; lane = feature d. acc_h = sum_e alpha_h * z[src][h*DH+d];
// x[n][d] = maybe_relu(max_h(acc_h + bg[h*DH+d])). Atomic-free.
template <int DH>
__global__ __launch_bounds__(256) void gat_gather(const int* __restrict__ rowstart,
                                                  const int* __restrict__ cnt,
                                                  const int* __restrict__ esrc,
                                                  const float* __restrict__ aebuf,
                                                  const float* __restrict__ z,
                                                  const float* __restrict__ bg,
                                                  float* __restrict__ x, int do_relu) {
    constexpr int CO = HH * DH;
    int n = blockIdx.x * 4 + (threadIdx.x >> 6);
    if (n >= NN) return;
    const int lane = threadIdx.x & 63;
    const int s0 = rowstart[n];
    const int deg = cnt[n];
    float a0 = 0.f, a1 = 0.f, a2 = 0.f;
    for (int i = 0; i < deg; ++i) {
        int s = esrc[s0 + i];
        float w0 = aebuf[(size_t)(s0 + i) * HH + 0];
        float w1 = aebuf[(size_t)(s0 + i) * HH + 1];
        float w2 = aebuf[(size_t)(s0 + i) * HH + 2];
        const float* zr = z + (size_t)s * CO;
        if (lane < DH) {
            a0 += w0 * zr[lane];
            a1 += w1 * zr[DH + lane];
            a2 += w2 * zr[2 * DH + lane];
        }
    }
    if (lane < DH) {
        float m = fmaxf(fmaxf(a0 + bg[lane], a1 + bg[DH + lane]), a2 + bg[2 * DH + lane]);
        if (do_relu) m = fmaxf(m, 0.f);
        x[(size_t)n * DH + lane] = m;
    }
}

// ---------------------------------------------------------------- GCN gather (atomic-free)
// agg[n] = rdin[n] * sum_e rdout[src] * x[src]
template <int K>
__global__ __launch_bounds__(256) void gcn_gather(const int* __restrict__ rowstart,
                                                  const int* __restrict__ cnt,
                                                  const int* __restrict__ esrc,
                                                  const float* __restrict__ xin,
                                                  const float* __restrict__ rdout,
                                                  const float* __restrict__ rdin,
                                                  float* __restrict__ agg) {
    int n = blockIdx.x * 4 + (threadIdx.x >> 6);
    if (n >= NN) return;
    const int lane = threadIdx.x & 63;
    const int s0 = rowstart[n];
    const int deg = cnt[n];
    float acc0 = 0.f, acc1 = 0.f;
    for (int i = 0; i < deg; ++i) {
        int s = esrc[s0 + i];
        float sc = rdout[s];
        const float* xr = xin + (size_t)s * K;
        if (lane < K) acc0 += sc * xr[lane];
        if (K > 64 && lane + 64 < K) acc1 += sc * xr[lane + 64];
    }
    const float ri = rdin[n];
    if (lane < K) agg[(size_t)n * K + lane] = acc0 * ri;
    if (K > 64 && lane + 64 < K) agg[(size_t)n * K + lane + 64] = acc1 * ri;
}

// out = relu( in @ W + b ),  (N x K) @ (K x 96); rdin scaling already in `in`.
template <int K>
__global__ __launch_bounds__(192) void gcn_gemm(const float* __restrict__ in,
                                                const float* __restrict__ W,
                                                const float* __restrict__ bias,
                                                float* __restrict__ out) {
    __shared__ float Wl[K * HD];
    __shared__ float hs[RROWS * K];
    __shared__ float bl[HD];
    const int tid = threadIdx.x;
    for (int i = tid; i < K * HD; i += 192) Wl[i] = W[i];
    if (tid < HD) bl[tid] = bias[tid];
    const int base = blockIdx.x * RROWS;
    const int nrow = min(RROWS, NN - base);
    for (int i = tid; i < nrow * K; i += 192) hs[i] = in[(size_t)base * K + i];
    __syncthreads();
    const int co = tid % HD;
    const int grp = tid / HD;  // 0..1, each handles 8 rows
    float acc[8];
#pragma unroll
    for (int j = 0; j < 8; ++j) acc[j] = bl[co];
#pragma unroll 4
    for (int k = 0; k < K; ++k) {
        float w = Wl[k * HD + co];
#pragma unroll
        for (int j = 0; j < 8; ++j) acc[j] += hs[(grp * 8 + j) * K + k] * w;
    }
#pragma unroll
    for (int j = 0; j < 8; ++j) {
        int r = grp * 8 + j;
        if (r < nrow) out[(size_t)(base + r) * HD + co] = fmaxf(acc[j], 0.f);
    }
}

// ---------------------------------------------------------------- pooling + heads
// One block per PBLK contiguous nodes; 96 threads = one per feature column.
// gid is sorted -> register-run accumulation, ~1 atomic per (run, feature).
__global__ __launch_bounds__(96) void pool_k(const float* __restrict__ x,
                                             const int* __restrict__ gid,
                                             float* __restrict__ s,
                                             float* __restrict__ c) {
    const int f = threadIdx.x;  // 0..95
    const int n0 = blockIdx.x * PBLK;
    const int n1 = min(n0 + PBLK, NN);
    int cur = gid[n0];
    float acc = 0.f;
    int cnt = 0;
    for (int n = n0; n < n1; ++n) {
        int g = gid[n];  // wave-uniform
        if (g != cur) {
            unsafeAtomicAdd(&s[cur * HD + f], acc);
            if (f == 0) unsafeAtomicAdd(&c[cur], (float)cnt);
            acc = 0.f;
            cnt = 0;
            cur = g;
        }
        acc += x[(size_t)n * HD + f];
        ++cnt;
    }
    unsafeAtomicAdd(&s[cur * HD + f], acc);
    if (f == 0) unsafeAtomicAdd(&c[cur], (float)cnt);
}

__global__ void weight_k(const float* __restrict__ x3, float* __restrict__ w) {
    int n = blockIdx.x * blockDim.x + threadIdx.x;
    if (n >= NN) return;
    w[n] = x3[(size_t)n * HD + 78];
}

__global__ __launch_bounds__(96) void final_k(
    const float* __restrict__ s1, const float* __restrict__ s2, const float* __restrict__ s3,
    const float* __restrict__ c1, const float* __restrict__ c2, const float* __restrict__ c3,
    const float* __restrict__ Wr1, const float* __restrict__ br1,
    const float* __restrict__ Wr2, const float* __restrict__ br2,
    const float* __restrict__ Wcl, const float* __restrict__ bcl,
    float* __restrict__ r1, float* __restrict__ r2, float* __restrict__ cls,
    float* __restrict__ hg3) {
    __shared__ float sh[HD];
    int g = blockIdx.x, f = threadIdx.x;
    float h1v = s1[g * HD + f] / fmaxf(c1[g], 1.f);
    float h2v = s2[g * HD + f] / fmaxf(c2[g], 1.f);
    float h3v = s3[g * HD + f] / fmaxf(c3[g], 1.f);
    hg3[g * HD + f] = h3v;
    sh[f] = h1v * Wr1[f];
    __syncthreads();
    if (f == 0) {
        float t = 0.f;
        for (int i = 0; i < HD; ++i) t += sh[i];
        r1[g] = t + br1[0];
    }
    __syncthreads();
    sh[f] = h2v * Wr2[f];
    __syncthreads();
    if (f == 0) {
        float t = 0.f;
        for (int i = 0; i < HD; ++i) t += sh[i];
        r2[g] = t + br2[0];
    }
    __syncthreads();
    for (int c = 0; c < 10; ++c) {
        sh[f] = h3v * Wcl[f * 10 + c];
        __syncthreads();
        if (f == 0) {
            float t = 0.f;
            for (int i = 0; i < HD; ++i) t += sh[i];
            cls[g * 10 + c] = t + bcl[c];
        }
        __syncthreads();
    }
}

// ---------------------------------------------------------------- host side

struct WS {
    float *z, *xbuf, *ybuf, *el, *er, *aebuf, *rdout, *rdin, *wal, *war;
    int *cin, *cout, *rowstart, *cursor, *esrc, *eorig;
};

template <int DH>
static void run_graph(const float* h, const int* src, const int* dst, const int* gid,
                      const float* Wg, const float* al, const float* ar, const float* bg,
                      const float* Wf, const float* bf, const float* W2, const float* b2,
                      int relu_epi, float* attn, float* pool_s, float* pool_c,
                      const WS& w, hipStream_t st) {
    const int nb = (NN + RROWS - 1) / RROWS;
    const int eb = (NE + 255) / 256;
    const int nb256 = (NN + 255) / 256;
    const int wb = (NN + 3) / 4;  // wave-per-node blocks

    gatz_gemm<DH, DH><<<NN / 64, 192, 0, st>>>(h, Wg, w.z);
    waler_k<DH, DH><<<1, 192, 0, st>>>(Wg, al, ar, w.wal, w.war);
    el_er_k<DH><<<(NN + 127) / 128, 128, 0, st>>>(h, w.wal, w.war, w.el, w.er);

    // CSR build (dst-sorted) + degrees
    hipMemsetAsync(w.cin, 0, NN * sizeof(int), st);
    hipMemsetAsync(w.cout, 0, NN * sizeof(int), st);
    hist_k<<<eb, 256, 0, st>>>(src, dst, w.cin, w.cout);
    scan_k<<<1, 1024, 0, st>>>(w.cin, w.rowstart, w.cursor);
    fill_k<<<eb, 256, 0, st>>>(src, dst, w.cursor, w.esrc, w.eorig);
    rsqrt_k<<<nb256, 256, 0, st>>>(w.cin, w.cout, w.rdin, w.rdout);

    gat_softmax<<<nb256, 256, 0, st>>>(w.rowstart, w.cin, w.esrc, w.eorig,
                                       w.el, w.er, w.aebuf, attn);
    gat_gather<DH><<<wb, 256, 0, st>>>(w.rowstart, w.cin, w.esrc, w.aebuf, w.z,
                                       bg, w.xbuf, relu_epi);

    // GCN layer 1: xbuf (width DH) -> ybuf (width DH, rdin-scaled) -> xbuf (96)
    gcn_gather<DH><<<wb, 256, 0, st>>>(w.rowstart, w.cin, w.esrc, w.xbuf,
                                       w.rdout, w.rdin, w.ybuf);
    gcn_gemm<DH><<<nb, 192, 0, st>>>(w.ybuf, Wf, bf, w.xbuf);
    // GCN layer 2: xbuf (96) -> ybuf (96) -> xbuf (96)
    gcn_gather<HD><<<wb, 256, 0, st>>>(w.rowstart, w.cin, w.esrc, w.xbuf,
                                       w.rdout, w.rdin, w.ybuf);
    gcn_gemm<HD><<<nb, 192, 0, st>>>(w.ybuf, W2, b2, w.xbuf);

    hipMemsetAsync(pool_s, 0, NG * HD * sizeof(float), st);
    hipMemsetAsync(pool_c, 0, NG * sizeof(float), st);
    pool_k<<<(NN + PBLK - 1) / PBLK, 96, 0, st>>>(w.xbuf, gid, pool_s, pool_c);
}

extern "C" void kernel_launch(void* const* d_in, const int* in_sizes, int n_in,
                              void* d_out, int out_size, void* d_ws, size_t ws_size,
                              hipStream_t stream) {
    (void)in_sizes; (void)n_in; (void)out_size; (void)ws_size;
    const float* h1 = (const float*)d_in[0];
    const float* h2 = (const float*)d_in[1];
    const float* h3 = (const float*)d_in[2];
    const int* src1 = (const int*)d_in[3];
    const int* dst1 = (const int*)d_in[4];
    const int* gid1 = (const int*)d_in[5];
    const int* src2 = (const int*)d_in[6];
    const int* dst2 = (const int*)d_in[7];
    const int* gid2 = (const int*)d_in[8];
    const int* src3 = (const int*)d_in[9];
    const int* dst3 = (const int*)d_in[10];
    const int* gid3 = (const int*)d_in[11];
    const float* Wg1 = (const float*)d_in[12];
    const float* al1 = (const float*)d_in[13];
    const float* ar1 = (const float*)d_in[14];
    const float* bg1 = (const float*)d_in[15];
    const float* Wg2 = (const float*)d_in[16];
    const float* al2 = (const float*)d_in[17];
    const float* ar2 = (const float*)d_in[18];
    const float* bg2 = (const float*)d_in[19];
    const float* Wc1 = (const float*)d_in[20];
    const float* bc1 = (const float*)d_in[21];
    const float* Wc2 = (const float*)d_in[22];
    const float* bc2 = (const float*)d_in[23];
    const float* Wc3 = (const float*)d_in[24];
    const float* bc3 = (const float*)d_in[25];
    const float* Wr1 = (const float*)d_in[26];
    const float* br1 = (const float*)d_in[27];
    const float* Wr2 = (const float*)d_in[28];
    const float* br2 = (const float*)d_in[29];
    const float* Wcl = (const float*)d_in[30];
    const float* bcl = (const float*)d_in[31];

    float* out = (float*)d_out;
    float* o_r1 = out + 0;
    float* o_r2 = out + 100;
    float* o_cls = out + 200;
    float* o_attn1 = out + 1200;
    float* o_attn3 = out + 401200;
    float* o_weight = out + 801200;
    float* o_hg3 = out + 841200;

    // workspace layout
    float* ws = (float*)d_ws;
    size_t off = 0;
    WS w;
    w.z = ws + off;     off += (size_t)NN * 192;
    w.xbuf = ws + off;  off += (size_t)NN * HD;
    w.ybuf = ws + off;  off += (size_t)NN * HD;
    w.el = ws + off;    off += (size_t)NN * HH;
    w.er = ws + off;    off += (size_t)NN * HH;
    w.aebuf = ws + off; off += (size_t)NE * HH;
    w.rdout = ws + off; off += NN;
    w.rdin = ws + off;  off += NN;
    w.wal = ws + off;   off += 192;
    w.war = ws + off;   off += 192;
    float* s1 = ws + off; off += NG * HD;
    float* s2 = ws + off; off += NG * HD;
    float* s3 = ws + off; off += NG * HD;
    float* c1 = ws + off; off += NG;
    float* c2 = ws + off; off += NG;
    float* c3 = ws + off; off += NG;
    w.cin = (int*)(ws + off);      off += NN;
    w.cout = (int*)(ws + off);     off += NN;
    w.rowstart = (int*)(ws + off); off += NN;
    w.cursor = (int*)(ws + off);   off += NN;
    w.esrc = (int*)(ws + off);     off += NE;
    w.eorig = (int*)(ws + off);    off += NE;

    // graph 1: GAT(Wg1, Dh=63) -> relu(max) -> GCN(Wc3) -> GCN(Wc2), attn out
    run_graph<63>(h1, src1, dst1, gid1, Wg1, al1, ar1, bg1, Wc3, bc3, Wc2, bc2,
                  1, o_attn1, s1, c1, w, stream);
    // graph 2: same GAT weights, no relu on max, no attn out
    run_graph<63>(h2, src2, dst2, gid2, Wg1, al1, ar1, bg1, Wc3, bc3, Wc2, bc2,
                  0, nullptr, s2, c2, w, stream);
    // graph 3: GAT(Wg2, Dh=64), no relu on max, attn out; GCN(Wc1) then GCN(Wc2)
    run_graph<64>(h3, src3, dst3, gid3, Wg2, al2, ar2, bg2, Wc1, bc1, Wc2, bc2,
                  0, o_attn3, s3, c3, w, stream);

    weight_k<<<(NN + 255) / 256, 256, 0, stream>>>(w.xbuf, o_weight);
    final_k<<<NG, 96, 0, stream>>>(s1, s2, s3, c1, c2, c3, Wr1, br1, Wr2, br2,
                                   Wcl, bcl, o_r1, o_r2, o_cls, o_hg3);
}

// Round 9
// 1411.040 us; speedup vs baseline: 3.1270x; 1.1745x over previous
//
#include <hip/hip_runtime.h>

#define NN 40000
#define NE 400000
#define NG 100
#define HH 3
#define HD 96

static constexpr int RROWS = 16;  // rows per block in node GEMMs
static constexpr int PBLK = 128;  // nodes per block in pool_k
static constexpr int SCB = 256;   // scan block size
static constexpr int NSB = (NN + SCB - 1) / SCB;  // 157 scan blocks

// ---------------------------------------------------------------- GAT z GEMM (register-tiled)
// z = h @ Wg  (N x DIN) @ (DIN x 3*DH). Block = 64 rows x 192 cols, 192 threads,
// each thread an 8x8 register tile (cols interleaved at stride 24).
template <int DIN, int DH>
__global__ __launch_bounds__(192) void gatz_gemm(const float* __restrict__ h,
                                                 const float* __restrict__ W,
                                                 float* __restrict__ z) {
    constexpr int CO = HH * DH;   // 189 or 192
    constexpr int COP = 192;      // padded col count (= blockDim)
    constexpr int KP = 64;        // padded K
    constexpr int HSTR = 65;      // hsl row stride (65%32=1 -> conflict-free)
    __shared__ float Wl[KP * COP];
    __shared__ float hsl[64 * HSTR];
    const int tid = threadIdx.x;
#pragma unroll 1
    for (int k = 0; k < KP; ++k)
        Wl[k * COP + tid] = (k < DIN && tid < CO) ? W[k * CO + tid] : 0.f;
    const int base = blockIdx.x * 64;
#pragma unroll 1
    for (int idx = tid; idx < 64 * KP; idx += 192) {
        int r = idx >> 6, k = idx & 63;
        hsl[r * HSTR + k] = (k < DIN) ? h[(size_t)(base + r) * DIN + k] : 0.f;
    }
    __syncthreads();
    const int rt = tid / 24;  // 0..7 -> rows rt*8..rt*8+7
    const int ct = tid % 24;  // cols ct + 24*j, j=0..7
    const int r0 = rt * 8;
    float acc[8][8];
#pragma unroll
    for (int i = 0; i < 8; ++i)
#pragma unroll
        for (int j = 0; j < 8; ++j) acc[i][j] = 0.f;
#pragma unroll 2
    for (int k = 0; k < KP; ++k) {
        float hv[8], wv[8];
#pragma unroll
        for (int i = 0; i < 8; ++i) hv[i] = hsl[(r0 + i) * HSTR + k];
#pragma unroll
        for (int j = 0; j < 8; ++j) wv[j] = Wl[k * COP + ct + 24 * j];
#pragma unroll
        for (int i = 0; i < 8; ++i)
#pragma unroll
            for (int j = 0; j < 8; ++j) acc[i][j] += hv[i] * wv[j];
    }
#pragma unroll
    for (int i = 0; i < 8; ++i) {
        const size_t row = base + r0 + i;
#pragma unroll
        for (int j = 0; j < 8; ++j) {
            int c = ct + 24 * j;
            if (c < CO) z[row * CO + c] = acc[i][j];
        }
    }
}

// Wal[k][h] = sum_d W[k][h*DH+d]*al[h][d]  (folds el = z@al into h@(W@al))
template <int DIN, int DH>
__global__ __launch_bounds__(192) void waler_k(const float* __restrict__ W,
                                               const float* __restrict__ al,
                                               const float* __restrict__ ar,
                                               float* __restrict__ Wal,
                                               float* __restrict__ War) {
    constexpr int CO = HH * DH;
    const int t = threadIdx.x;
    if (t >= DIN * HH) return;
    const int k = t / HH, hd = t % HH;
    float sl = 0.f, sr = 0.f;
    for (int d = 0; d < DH; ++d) {
        float wv = W[k * CO + hd * DH + d];
        sl += wv * al[hd * DH + d];
        sr += wv * ar[hd * DH + d];
    }
    Wal[k * HH + hd] = sl;
    War[k * HH + hd] = sr;
}

// el[n][h] = h[n] . Wal[:,h] ; er likewise.
template <int DIN>
__global__ __launch_bounds__(128) void el_er_k(const float* __restrict__ h,
                                               const float* __restrict__ Wal,
                                               const float* __restrict__ War,
                                               float* __restrict__ el,
                                               float* __restrict__ er) {
    constexpr int STR = (DIN % 2 == 0) ? DIN + 1 : DIN;  // 63->63, 64->65
    __shared__ float hsl[128 * STR];
    __shared__ float walS[DIN * HH], warS[DIN * HH];
    const int t = threadIdx.x;
    const int base = blockIdx.x * 128;
    const int nrow = min(128, NN - base);
    for (int idx = t; idx < nrow * DIN; idx += 128) {
        int r = idx / DIN, k = idx - r * DIN;
        hsl[r * STR + k] = h[(size_t)base * DIN + idx];
    }
    for (int idx = t; idx < DIN * HH; idx += 128) {
        walS[idx] = Wal[idx];
        warS[idx] = War[idx];
    }
    __syncthreads();
    if (t >= nrow) return;
    float e0 = 0.f, e1 = 0.f, e2 = 0.f, f0 = 0.f, f1 = 0.f, f2 = 0.f;
    for (int k = 0; k < DIN; ++k) {
        float hv = hsl[t * STR + k];
        e0 += hv * walS[k * HH + 0];
        e1 += hv * walS[k * HH + 1];
        e2 += hv * walS[k * HH + 2];
        f0 += hv * warS[k * HH + 0];
        f1 += hv * warS[k * HH + 1];
        f2 += hv * warS[k * HH + 2];
    }
    const int n = base + t;
    el[n * HH + 0] = e0; el[n * HH + 1] = e1; el[n * HH + 2] = e2;
    er[n * HH + 0] = f0; er[n * HH + 1] = f1; er[n * HH + 2] = f2;
}

// ---------------------------------------------------------------- CSR build
__global__ void hist_k(const int* __restrict__ src, const int* __restrict__ dst,
                       int* __restrict__ cin, int* __restrict__ cout) {
    int e = blockIdx.x * blockDim.x + threadIdx.x;
    if (e >= NE) return;
    atomicAdd(&cin[dst[e]], 1);
    atomicAdd(&cout[src[e]], 1);
}

// 3-phase device-wide exclusive scan of cin -> rowstart (+cursor).
// Replaces the single-block scan_k (91 us, Occupancy 0.14%: one CU, serial
// stride-40 reads). All phases coalesced, 157-block parallel.
__global__ __launch_bounds__(SCB) void scan1_k(const int* __restrict__ cin,
                                               int* __restrict__ bsum) {
    __shared__ int sh[SCB];
    const int t = threadIdx.x;
    const int i = blockIdx.x * SCB + t;
    sh[t] = (i < NN) ? cin[i] : 0;
    __syncthreads();
    for (int o = SCB / 2; o > 0; o >>= 1) {
        if (t < o) sh[t] += sh[t + o];
        __syncthreads();
    }
    if (t == 0) bsum[blockIdx.x] = sh[0];
}

__global__ __launch_bounds__(SCB) void scan2_k(const int* __restrict__ bsum,
                                               int* __restrict__ boff) {
    __shared__ int sh[SCB];
    const int t = threadIdx.x;
    int v = (t < NSB) ? bsum[t] : 0;
    sh[t] = v;
    __syncthreads();
    for (int o = 1; o < SCB; o <<= 1) {
        int u = (t >= o) ? sh[t - o] : 0;
        __syncthreads();
        sh[t] += u;
        __syncthreads();
    }
    if (t < NSB) boff[t] = sh[t] - v;  // exclusive
}

__global__ __launch_bounds__(SCB) void scan3_k(const int* __restrict__ cin,
                                               const int* __restrict__ boff,
                                               int* __restrict__ rowstart,
                                               int* __restrict__ cursor) {
    __shared__ int sh[SCB];
    const int t = threadIdx.x;
    const int i = blockIdx.x * SCB + t;
    int v = (i < NN) ? cin[i] : 0;
    sh[t] = v;
    __syncthreads();
    for (int o = 1; o < SCB; o <<= 1) {
        int u = (t >= o) ? sh[t - o] : 0;
        __syncthreads();
        sh[t] += u;
        __syncthreads();
    }
    if (i < NN) {
        int rs = boff[blockIdx.x] + sh[t] - v;  // exclusive prefix
        rowstart[i] = rs;
        cursor[i] = rs;
    }
}

__global__ void fill_k(const int* __restrict__ src, const int* __restrict__ dst,
                       int* __restrict__ cursor, int* __restrict__ esrc,
                       int* __restrict__ eorig) {
    int e = blockIdx.x * blockDim.x + threadIdx.x;
    if (e >= NE) return;
    int pos = atomicAdd(&cursor[dst[e]], 1);
    esrc[pos] = src[e];
    eorig[pos] = e;
}

__global__ void rsqrt_k(const int* __restrict__ cin, const int* __restrict__ cout,
                        float* __restrict__ rdin, float* __restrict__ rdout) {
    int n = blockIdx.x * blockDim.x + threadIdx.x;
    if (n >= NN) return;
    rdin[n] = 1.f / sqrtf((float)max(cin[n], 1));
    rdout[n] = 1.f / sqrtf((float)max(cout[n], 1));
}

// ---------------------------------------------------------------- GAT softmax (per dst node, serial over CSR row)
__global__ void gat_softmax(const int* __restrict__ rowstart, const int* __restrict__ cnt,
                            const int* __restrict__ esrc, const int* __restrict__ eorig,
                            const float* __restrict__ el, const float* __restrict__ er,
                            float* __restrict__ aebuf, float* __restrict__ attn) {
    int n = blockIdx.x * blockDim.x + threadIdx.x;
    if (n >= NN) return;
    const int s0 = rowstart[n];
    const int deg = cnt[n];
    if (deg == 0) return;
    const float er0 = er[n * HH + 0], er1 = er[n * HH + 1], er2 = er[n * HH + 2];
    float m0 = -3.4e38f, m1 = -3.4e38f, m2 = -3.4e38f;
    for (int i = 0; i < deg; ++i) {
        int s = esrc[s0 + i];
        float v0 = el[s * HH + 0] + er0;
        float v1 = el[s * HH + 1] + er1;
        float v2 = el[s * HH + 2] + er2;
        v0 = v0 > 0.f ? v0 : 0.2f * v0;
        v1 = v1 > 0.f ? v1 : 0.2f * v1;
        v2 = v2 > 0.f ? v2 : 0.2f * v2;
        aebuf[(size_t)(s0 + i) * HH + 0] = v0;
        aebuf[(size_t)(s0 + i) * HH + 1] = v1;
        aebuf[(size_t)(s0 + i) * HH + 2] = v2;
        m0 = fmaxf(m0, v0); m1 = fmaxf(m1, v1); m2 = fmaxf(m2, v2);
    }
    float d0 = 0.f, d1 = 0.f, d2 = 0.f;
    for (int i = 0; i < deg; ++i) {
        float p0 = expf(aebuf[(size_t)(s0 + i) * HH + 0] - m0);
        float p1 = expf(aebuf[(size_t)(s0 + i) * HH + 1] - m1);
        float p2 = expf(aebuf[(size_t)(s0 + i) * HH + 2] - m2);
        aebuf[(size_t)(s0 + i) * HH + 0] = p0;
        aebuf[(size_t)(s0 + i) * HH + 1] = p1;
        aebuf[(size_t)(s0 + i) * HH + 2] = p2;
        d0 += p0; d1 += p1; d2 += p2;
    }
    const float i0 = 1.f / d0, i1 = 1.f / d1, i2 = 1.f / d2;
    for (int i = 0; i < deg; ++i) {
        float a0 = aebuf[(size_t)(s0 + i) * HH + 0] * i0;
        float a1 = aebuf[(size_t)(s0 + i) * HH + 1] * i1;
        float a2 = aebuf[(size_t)(s0 + i) * HH + 2] * i2;
        aebuf[(size_t)(s0 + i) * HH + 0] = a0;
        aebuf[(size_t)(s0 + i) * HH + 1] = a1;
        aebuf[(size_t)(s0 + i) * HH + 2] = a2;
        if (attn) attn[eorig[s0 + i]] = fmaxf(fmaxf(a0, a1), a2);
    }
}

// ---------------------------------------------------------------- GAT gather + fused epilogue
template <int DH>
__global__ __launch_bounds__(256) void gat_gather(const int* __restrict__ rowstart,
                                                  const int* __restrict__ cnt,
                                                  const int* __restrict__ esrc,
                                                  const float* __restrict__ aebuf,
                                                  const float* __restrict__ z,
                                                  const float* __restrict__ bg,
                                                  float* __restrict__ x, int do_relu) {
    constexpr int CO = HH * DH;
    int n = blockIdx.x * 4 + (threadIdx.x >> 6);
    if (n >= NN) return;
    const int lane = threadIdx.x & 63;
    const int s0 = rowstart[n];
    const int deg = cnt[n];
    float a0 = 0.f, a1 = 0.f, a2 = 0.f;
    for (int i = 0; i < deg; ++i) {
        int s = esrc[s0 + i];
        float w0 = aebuf[(size_t)(s0 + i) * HH + 0];
        float w1 = aebuf[(size_t)(s0 + i) * HH + 1];
        float w2 = aebuf[(size_t)(s0 + i) * HH + 2];
        const float* zr = z + (size_t)s * CO;
        if (lane < DH) {
            a0 += w0 * zr[lane];
            a1 += w1 * zr[DH + lane];
            a2 += w2 * zr[2 * DH + lane];
        }
    }
    if (lane < DH) {
        float m = fmaxf(fmaxf(a0 + bg[lane], a1 + bg[DH + lane]), a2 + bg[2 * DH + lane]);
        if (do_relu) m = fmaxf(m, 0.f);
        x[(size_t)n * DH + lane] = m;
    }
}

// ---------------------------------------------------------------- GCN gather (atomic-free)
template <int K>
__global__ __launch_bounds__(256) void gcn_gather(const int* __restrict__ rowstart,
                                                  const int* __restrict__ cnt,
                                                  const int* __restrict__ esrc,
                                                  const float* __restrict__ xin,
                                                  const float* __restrict__ rdout,
                                                  const float* __restrict__ rdin,
                                                  float* __restrict__ agg) {
    int n = blockIdx.x * 4 + (threadIdx.x >> 6);
    if (n >= NN) return;
    const int lane = threadIdx.x & 63;
    const int s0 = rowstart[n];
    const int deg = cnt[n];
    float acc0 = 0.f, acc1 = 0.f;
    for (int i = 0; i < deg; ++i) {
        int s = esrc[s0 + i];
        float sc = rdout[s];
        const float* xr = xin + (size_t)s * K;
        if (lane < K) acc0 += sc * xr[lane];
        if (K > 64 && lane + 64 < K) acc1 += sc * xr[lane + 64];
    }
    const float ri = rdin[n];
    if (lane < K) agg[(size_t)n * K + lane] = acc0 * ri;
    if (K > 64 && lane + 64 < K) agg[(size_t)n * K + lane + 64] = acc1 * ri;
}

// out = relu( in @ W + b ),  (N x K) @ (K x 96); rdin scaling already in `in`.
template <int K>
__global__ __launch_bounds__(192) void gcn_gemm(const float* __restrict__ in,
                                                const float* __restrict__ W,
                                                const float* __restrict__ bias,
                                                float* __restrict__ out) {
    __shared__ float Wl[K * HD];
    __shared__ float hs[RROWS * K];
    __shared__ float bl[HD];
    const int tid = threadIdx.x;
    for (int i = tid; i < K * HD; i += 192) Wl[i] = W[i];
    if (tid < HD) bl[tid] = bias[tid];
    const int base = blockIdx.x * RROWS;
    const int nrow = min(RROWS, NN - base);
    for (int i = tid; i < nrow * K; i += 192) hs[i] = in[(size_t)base * K + i];
    __syncthreads();
    const int co = tid % HD;
    const int grp = tid / HD;  // 0..1, each handles 8 rows
    float acc[8];
#pragma unroll
    for (int j = 0; j < 8; ++j) acc[j] = bl[co];
#pragma unroll 4
    for (int k = 0; k < K; ++k) {
        float w = Wl[k * HD + co];
#pragma unroll
        for (int j = 0; j < 8; ++j) acc[j] += hs[(grp * 8 + j) * K + k] * w;
    }
#pragma unroll
    for (int j = 0; j < 8; ++j) {
        int r = grp * 8 + j;
        if (r < nrow) out[(size_t)(base + r) * HD + co] = fmaxf(acc[j], 0.f);
    }
}

// ---------------------------------------------------------------- pooling + heads
__global__ __launch_bounds__(96) void pool_k(const float* __restrict__ x,
                                             const int* __restrict__ gid,
                                             float* __restrict__ s,
                                             float* __restrict__ c) {
    const int f = threadIdx.x;  // 0..95
    const int n0 = blockIdx.x * PBLK;
    const int n1 = min(n0 + PBLK, NN);
    int cur = gid[n0];
    float acc = 0.f;
    int cnt = 0;
    for (int n = n0; n < n1; ++n) {
        int g = gid[n];  // wave-uniform
        if (g != cur) {
            unsafeAtomicAdd(&s[cur * HD + f], acc);
            if (f == 0) unsafeAtomicAdd(&c[cur], (float)cnt);
            acc = 0.f;
            cnt = 0;
            cur = g;
        }
        acc += x[(size_t)n * HD + f];
        ++cnt;
    }
    unsafeAtomicAdd(&s[cur * HD + f], acc);
    if (f == 0) unsafeAtomicAdd(&c[cur], (float)cnt);
}

__global__ void weight_k(const float* __restrict__ x3, float* __restrict__ w) {
    int n = blockIdx.x * blockDim.x + threadIdx.x;
    if (n >= NN) return;
    w[n] = x3[(size_t)n * HD + 78];
}

__global__ __launch_bounds__(96) void final_k(
    const float* __restrict__ s1, const float* __restrict__ s2, const float* __restrict__ s3,
    const float* __restrict__ c1, const float* __restrict__ c2, const float* __restrict__ c3,
    const float* __restrict__ Wr1, const float* __restrict__ br1,
    const float* __restrict__ Wr2, const float* __restrict__ br2,
    const float* __restrict__ Wcl, const float* __restrict__ bcl,
    float* __restrict__ r1, float* __restrict__ r2, float* __restrict__ cls,
    float* __restrict__ hg3) {
    __shared__ float sh[HD];
    int g = blockIdx.x, f = threadIdx.x;
    float h1v = s1[g * HD + f] / fmaxf(c1[g], 1.f);
    float h2v = s2[g * HD + f] / fmaxf(c2[g], 1.f);
    float h3v = s3[g * HD + f] / fmaxf(c3[g], 1.f);
    hg3[g * HD + f] = h3v;
    sh[f] = h1v * Wr1[f];
    __syncthreads();
    if (f == 0) {
        float t = 0.f;
        for (int i = 0; i < HD; ++i) t += sh[i];
        r1[g] = t + br1[0];
    }
    __syncthreads();
    sh[f] = h2v * Wr2[f];
    __syncthreads();
    if (f == 0) {
        float t = 0.f;
        for (int i = 0; i < HD; ++i) t += sh[i];
        r2[g] = t + br2[0];
    }
    __syncthreads();
    for (int c = 0; c < 10; ++c) {
        sh[f] = h3v * Wcl[f * 10 + c];
        __syncthreads();
        if (f == 0) {
            float t = 0.f;
            for (int i = 0; i < HD; ++i) t += sh[i];
            cls[g * 10 + c] = t + bcl[c];
        }
        __syncthreads();
    }
}

// ---------------------------------------------------------------- host side

struct WS {
    float *z, *xbuf, *ybuf, *el, *er, *aebuf, *rdout, *rdin, *wal, *war;
    int *cin, *cout, *rowstart, *cursor, *esrc, *eorig, *bsum, *boff;
};

template <int DH>
static void run_graph(const float* h, const int* src, const int* dst, const int* gid,
                      const float* Wg, const float* al, const float* ar, const float* bg,
                      const float* Wf, const float* bf, const float* W2, const float* b2,
                      int relu_epi, float* attn, float* pool_s, float* pool_c,
                      const WS& w, hipStream_t st) {
    const int nb = (NN + RROWS - 1) / RROWS;
    const int eb = (NE + 255) / 256;
    const int nb256 = (NN + 255) / 256;
    const int wb = (NN + 3) / 4;  // wave-per-node blocks

    gatz_gemm<DH, DH><<<NN / 64, 192, 0, st>>>(h, Wg, w.z);
    waler_k<DH, DH><<<1, 192, 0, st>>>(Wg, al, ar, w.wal, w.war);
    el_er_k<DH><<<(NN + 127) / 128, 128, 0, st>>>(h, w.wal, w.war, w.el, w.er);

    // CSR build (dst-sorted) + degrees
    hipMemsetAsync(w.cin, 0, NN * sizeof(int), st);
    hipMemsetAsync(w.cout, 0, NN * sizeof(int), st);
    hist_k<<<eb, 256, 0, st>>>(src, dst, w.cin, w.cout);
    scan1_k<<<NSB, SCB, 0, st>>>(w.cin, w.bsum);
    scan2_k<<<1, SCB, 0, st>>>(w.bsum, w.boff);
    scan3_k<<<NSB, SCB, 0, st>>>(w.cin, w.boff, w.rowstart, w.cursor);
    fill_k<<<eb, 256, 0, st>>>(src, dst, w.cursor, w.esrc, w.eorig);
    rsqrt_k<<<nb256, 256, 0, st>>>(w.cin, w.cout, w.rdin, w.rdout);

    gat_softmax<<<nb256, 256, 0, st>>>(w.rowstart, w.cin, w.esrc, w.eorig,
                                       w.el, w.er, w.aebuf, attn);
    gat_gather<DH><<<wb, 256, 0, st>>>(w.rowstart, w.cin, w.esrc, w.aebuf, w.z,
                                       bg, w.xbuf, relu_epi);

    // GCN layer 1: xbuf (width DH) -> ybuf (width DH, rdin-scaled) -> xbuf (96)
    gcn_gather<DH><<<wb, 256, 0, st>>>(w.rowstart, w.cin, w.esrc, w.xbuf,
                                       w.rdout, w.rdin, w.ybuf);
    gcn_gemm<DH><<<nb, 192, 0, st>>>(w.ybuf, Wf, bf, w.xbuf);
    // GCN layer 2: xbuf (96) -> ybuf (96) -> xbuf (96)
    gcn_gather<HD><<<wb, 256, 0, st>>>(w.rowstart, w.cin, w.esrc, w.xbuf,
                                       w.rdout, w.rdin, w.ybuf);
    gcn_gemm<HD><<<nb, 192, 0, st>>>(w.ybuf, W2, b2, w.xbuf);

    hipMemsetAsync(pool_s, 0, NG * HD * sizeof(float), st);
    hipMemsetAsync(pool_c, 0, NG * sizeof(float), st);
    pool_k<<<(NN + PBLK - 1) / PBLK, 96, 0, st>>>(w.xbuf, gid, pool_s, pool_c);
}

extern "C" void kernel_launch(void* const* d_in, const int* in_sizes, int n_in,
                              void* d_out, int out_size, void* d_ws, size_t ws_size,
                              hipStream_t stream) {
    (void)in_sizes; (void)n_in; (void)out_size; (void)ws_size;
    const float* h1 = (const float*)d_in[0];
    const float* h2 = (const float*)d_in[1];
    const float* h3 = (const float*)d_in[2];
    const int* src1 = (const int*)d_in[3];
    const int* dst1 = (const int*)d_in[4];
    const int* gid1 = (const int*)d_in[5];
    const int* src2 = (const int*)d_in[6];
    const int* dst2 = (const int*)d_in[7];
    const int* gid2 = (const int*)d_in[8];
    const int* src3 = (const int*)d_in[9];
    const int* dst3 = (const int*)d_in[10];
    const int* gid3 = (const int*)d_in[11];
    const float* Wg1 = (const float*)d_in[12];
    const float* al1 = (const float*)d_in[13];
    const float* ar1 = (const float*)d_in[14];
    const float* bg1 = (const float*)d_in[15];
    const float* Wg2 = (const float*)d_in[16];
    const float* al2 = (const float*)d_in[17];
    const float* ar2 = (const float*)d_in[18];
    const float* bg2 = (const float*)d_in[19];
    const float* Wc1 = (const float*)d_in[20];
    const float* bc1 = (const float*)d_in[21];
    const float* Wc2 = (const float*)d_in[22];
    const float* bc2 = (const float*)d_in[23];
    const float* Wc3 = (const float*)d_in[24];
    const float* bc3 = (const float*)d_in[25];
    const float* Wr1 = (const float*)d_in[26];
    const float* br1 = (const float*)d_in[27];
    const float* Wr2 = (const float*)d_in[28];
    const float* br2 = (const float*)d_in[29];
    const float* Wcl = (const float*)d_in[30];
    const float* bcl = (const float*)d_in[31];

    float* out = (float*)d_out;
    float* o_r1 = out + 0;
    float* o_r2 = out + 100;
    float* o_cls = out + 200;
    float* o_attn1 = out + 1200;
    float* o_attn3 = out + 401200;
    float* o_weight = out + 801200;
    float* o_hg3 = out + 841200;

    // workspace layout
    float* ws = (float*)d_ws;
    size_t off = 0;
    WS w;
    w.z = ws + off;     off += (size_t)NN * 192;
    w.xbuf = ws + off;  off += (size_t)NN * HD;
    w.ybuf = ws + off;  off += (size_t)NN * HD;
    w.el = ws + off;    off += (size_t)NN * HH;
    w.er = ws + off;    off += (size_t)NN * HH;
    w.aebuf = ws + off; off += (size_t)NE * HH;
    w.rdout = ws + off; off += NN;
    w.rdin = ws + off;  off += NN;
    w.wal = ws + off;   off += 192;
    w.war = ws + off;   off += 192;
    float* s1 = ws + off; off += NG * HD;
    float* s2 = ws + off; off += NG * HD;
    float* s3 = ws + off; off += NG * HD;
    float* c1 = ws + off; off += NG;
    float* c2 = ws + off; off += NG;
    float* c3 = ws + off; off += NG;
    w.cin = (int*)(ws + off);      off += NN;
    w.cout = (int*)(ws + off);     off += NN;
    w.rowstart = (int*)(ws + off); off += NN;
    w.cursor = (int*)(ws + off);   off += NN;
    w.esrc = (int*)(ws + off);     off += NE;
    w.eorig = (int*)(ws + off);    off += NE;
    w.bsum = (int*)(ws + off);     off += NSB;
    w.boff = (int*)(ws + off);     off += NSB;

    // graph 1: GAT(Wg1, Dh=63) -> relu(max) -> GCN(Wc3) -> GCN(Wc2), attn out
    run_graph<63>(h1, src1, dst1, gid1, Wg1, al1, ar1, bg1, Wc3, bc3, Wc2, bc2,
                  1, o_attn1, s1, c1, w, stream);
    // graph 2: same GAT weights, no relu on max, no attn out
    run_graph<63>(h2, src2, dst2, gid2, Wg1, al1, ar1, bg1, Wc3, bc3, Wc2, bc2,
                  0, nullptr, s2, c2, w, stream);
    // graph 3: GAT(Wg2, Dh=64), no relu on max, attn out; GCN(Wc1) then GCN(Wc2)
    run_graph<64>(h3, src3, dst3, gid3, Wg2, al2, ar2, bg2, Wc1, bc1, Wc2, bc2,
                  0, o_attn3, s3, c3, w, stream);

    weight_k<<<(NN + 255) / 256, 256, 0, stream>>>(w.xbuf, o_weight);
    final_k<<<NG, 96, 0, stream>>>(s1, s2, s3, c1, c2, c3, Wr1, br1, Wr2, br2,
                                   Wcl, bcl, o_r1, o_r2, o_cls, o_hg3);
}

// Round 10
// 1335.118 us; speedup vs baseline: 3.3048x; 1.0569x over previous
//
#include <hip/hip_runtime.h>

#define NN 40000
#define NE 400000
#define NG 100
#define HH 3
#define HD 96

static constexpr int RROWS = 16;  // rows per block in node GEMMs
static constexpr int PBLK = 128;  // nodes per block in pool_k
static constexpr int SCB = 256;   // scan block size
static constexpr int NSB = (NN + SCB - 1) / SCB;  // 157 scan blocks

// ---------------------------------------------------------------- GAT z GEMM (register-tiled)
// z = h @ Wg  (N x DIN) @ (DIN x 3*DH). Block = 64 rows x 192 cols, 192 threads,
// each thread an 8x8 register tile (cols interleaved at stride 24).
// v2: W staged in two 32-k chunks (24.6 KB instead of 48 KB) -> LDS 41.2 KB
// -> 3 blocks/CU (9 waves) instead of 2 (6 waves), and the 625-block grid is
// fully resident in one round. v1 counters: 73 us, VALUBusy 12%, Occ 10%.
template <int DIN, int DH>
__global__ __launch_bounds__(192) void gatz_gemm(const float* __restrict__ h,
                                                 const float* __restrict__ W,
                                                 float* __restrict__ z) {
    constexpr int CO = HH * DH;   // 189 or 192
    constexpr int COP = 192;      // padded col count (= blockDim)
    constexpr int KP = 64;        // padded K
    constexpr int KC = 32;        // K staging chunk
    constexpr int HSTR = 65;      // hsl row stride (65%32=1 -> conflict-free)
    __shared__ float Wl[KC * COP];    // 24576 B
    __shared__ float hsl[64 * HSTR];  // 16640 B
    const int tid = threadIdx.x;
    const int base = blockIdx.x * 64;
    // stage h once: 64 rows (NN % 64 == 0), zero-pad k >= DIN
#pragma unroll 1
    for (int idx = tid; idx < 64 * KP; idx += 192) {
        int r = idx >> 6, k = idx & 63;
        hsl[r * HSTR + k] = (k < DIN) ? h[(size_t)(base + r) * DIN + k] : 0.f;
    }
    const int rt = tid / 24;  // 0..7 -> rows rt*8..rt*8+7
    const int ct = tid % 24;  // cols ct + 24*j, j=0..7
    const int r0 = rt * 8;
    float acc[8][8];
#pragma unroll
    for (int i = 0; i < 8; ++i)
#pragma unroll
        for (int j = 0; j < 8; ++j) acc[i][j] = 0.f;
#pragma unroll 1
    for (int kc = 0; kc < KP / KC; ++kc) {
        __syncthreads();  // kc=0: hsl ready; kc>0: all waves done reading Wl
#pragma unroll 4
        for (int k = 0; k < KC; ++k) {
            const int kg = kc * KC + k;
            Wl[k * COP + tid] = (kg < DIN && tid < CO) ? W[kg * CO + tid] : 0.f;
        }
        __syncthreads();
#pragma unroll 2
        for (int k = 0; k < KC; ++k) {
            float hv[8], wv[8];
#pragma unroll
            for (int i = 0; i < 8; ++i) hv[i] = hsl[(r0 + i) * HSTR + kc * KC + k];
#pragma unroll
            for (int j = 0; j < 8; ++j) wv[j] = Wl[k * COP + ct + 24 * j];
#pragma unroll
            for (int i = 0; i < 8; ++i)
#pragma unroll
                for (int j = 0; j < 8; ++j) acc[i][j] += hv[i] * wv[j];
        }
    }
#pragma unroll
    for (int i = 0; i < 8; ++i) {
        const size_t row = base + r0 + i;
#pragma unroll
        for (int j = 0; j < 8; ++j) {
            int c = ct + 24 * j;
            if (c < CO) z[row * CO + c] = acc[i][j];
        }
    }
}

// Wal[k][h] = sum_d W[k][h*DH+d]*al[h][d]  (folds el = z@al into h@(W@al))
template <int DIN, int DH>
__global__ __launch_bounds__(192) void waler_k(const float* __restrict__ W,
                                               const float* __restrict__ al,
                                               const float* __restrict__ ar,
                                               float* __restrict__ Wal,
                                               float* __restrict__ War) {
    constexpr int CO = HH * DH;
    const int t = threadIdx.x;
    if (t >= DIN * HH) return;
    const int k = t / HH, hd = t % HH;
    float sl = 0.f, sr = 0.f;
    for (int d = 0; d < DH; ++d) {
        float wv = W[k * CO + hd * DH + d];
        sl += wv * al[hd * DH + d];
        sr += wv * ar[hd * DH + d];
    }
    Wal[k * HH + hd] = sl;
    War[k * HH + hd] = sr;
}

// el[n][h] = h[n] . Wal[:,h] ; er likewise.
template <int DIN>
__global__ __launch_bounds__(128) void el_er_k(const float* __restrict__ h,
                                               const float* __restrict__ Wal,
                                               const float* __restrict__ War,
                                               float* __restrict__ el,
                                               float* __restrict__ er) {
    constexpr int STR = (DIN % 2 == 0) ? DIN + 1 : DIN;  // 63->63, 64->65
    __shared__ float hsl[128 * STR];
    __shared__ float walS[DIN * HH], warS[DIN * HH];
    const int t = threadIdx.x;
    const int base = blockIdx.x * 128;
    const int nrow = min(128, NN - base);
    for (int idx = t; idx < nrow * DIN; idx += 128) {
        int r = idx / DIN, k = idx - r * DIN;
        hsl[r * STR + k] = h[(size_t)base * DIN + idx];
    }
    for (int idx = t; idx < DIN * HH; idx += 128) {
        walS[idx] = Wal[idx];
        warS[idx] = War[idx];
    }
    __syncthreads();
    if (t >= nrow) return;
    float e0 = 0.f, e1 = 0.f, e2 = 0.f, f0 = 0.f, f1 = 0.f, f2 = 0.f;
    for (int k = 0; k < DIN; ++k) {
        float hv = hsl[t * STR + k];
        e0 += hv * walS[k * HH + 0];
        e1 += hv * walS[k * HH + 1];
        e2 += hv * walS[k * HH + 2];
        f0 += hv * warS[k * HH + 0];
        f1 += hv * warS[k * HH + 1];
        f2 += hv * warS[k * HH + 2];
    }
    const int n = base + t;
    el[n * HH + 0] = e0; el[n * HH + 1] = e1; el[n * HH + 2] = e2;
    er[n * HH + 0] = f0; er[n * HH + 1] = f1; er[n * HH + 2] = f2;
}

// ---------------------------------------------------------------- CSR build
__global__ void hist_k(const int* __restrict__ src, const int* __restrict__ dst,
                       int* __restrict__ cin, int* __restrict__ cout) {
    int e = blockIdx.x * blockDim.x + threadIdx.x;
    if (e >= NE) return;
    atomicAdd(&cin[dst[e]], 1);
    atomicAdd(&cout[src[e]], 1);
}

// 3-phase device-wide exclusive scan of cin -> rowstart (+cursor).
__global__ __launch_bounds__(SCB) void scan1_k(const int* __restrict__ cin,
                                               int* __restrict__ bsum) {
    __shared__ int sh[SCB];
    const int t = threadIdx.x;
    const int i = blockIdx.x * SCB + t;
    sh[t] = (i < NN) ? cin[i] : 0;
    __syncthreads();
    for (int o = SCB / 2; o > 0; o >>= 1) {
        if (t < o) sh[t] += sh[t + o];
        __syncthreads();
    }
    if (t == 0) bsum[blockIdx.x] = sh[0];
}

__global__ __launch_bounds__(SCB) void scan2_k(const int* __restrict__ bsum,
                                               int* __restrict__ boff) {
    __shared__ int sh[SCB];
    const int t = threadIdx.x;
    int v = (t < NSB) ? bsum[t] : 0;
    sh[t] = v;
    __syncthreads();
    for (int o = 1; o < SCB; o <<= 1) {
        int u = (t >= o) ? sh[t - o] : 0;
        __syncthreads();
        sh[t] += u;
        __syncthreads();
    }
    if (t < NSB) boff[t] = sh[t] - v;  // exclusive
}

__global__ __launch_bounds__(SCB) void scan3_k(const int* __restrict__ cin,
                                               const int* __restrict__ boff,
                                               int* __restrict__ rowstart,
                                               int* __restrict__ cursor) {
    __shared__ int sh[SCB];
    const int t = threadIdx.x;
    const int i = blockIdx.x * SCB + t;
    int v = (i < NN) ? cin[i] : 0;
    sh[t] = v;
    __syncthreads();
    for (int o = 1; o < SCB; o <<= 1) {
        int u = (t >= o) ? sh[t - o] : 0;
        __syncthreads();
        sh[t] += u;
        __syncthreads();
    }
    if (i < NN) {
        int rs = boff[blockIdx.x] + sh[t] - v;  // exclusive prefix
        rowstart[i] = rs;
        cursor[i] = rs;
    }
}

__global__ void fill_k(const int* __restrict__ src, const int* __restrict__ dst,
                       int* __restrict__ cursor, int* __restrict__ esrc,
                       int* __restrict__ eorig) {
    int e = blockIdx.x * blockDim.x + threadIdx.x;
    if (e >= NE) return;
    int pos = atomicAdd(&cursor[dst[e]], 1);
    esrc[pos] = src[e];
    eorig[pos] = e;
}

__global__ void rsqrt_k(const int* __restrict__ cin, const int* __restrict__ cout,
                        float* __restrict__ rdin, float* __restrict__ rdout) {
    int n = blockIdx.x * blockDim.x + threadIdx.x;
    if (n >= NN) return;
    rdin[n] = 1.f / sqrtf((float)max(cin[n], 1));
    rdout[n] = 1.f / sqrtf((float)max(cout[n], 1));
}

// ---------------------------------------------------------------- GAT softmax (per dst node, serial over CSR row)
__global__ void gat_softmax(const int* __restrict__ rowstart, const int* __restrict__ cnt,
                            const int* __restrict__ esrc, const int* __restrict__ eorig,
                            const float* __restrict__ el, const float* __restrict__ er,
                            float* __restrict__ aebuf, float* __restrict__ attn) {
    int n = blockIdx.x * blockDim.x + threadIdx.x;
    if (n >= NN) return;
    const int s0 = rowstart[n];
    const int deg = cnt[n];
    if (deg == 0) return;
    const float er0 = er[n * HH + 0], er1 = er[n * HH + 1], er2 = er[n * HH + 2];
    float m0 = -3.4e38f, m1 = -3.4e38f, m2 = -3.4e38f;
    for (int i = 0; i < deg; ++i) {
        int s = esrc[s0 + i];
        float v0 = el[s * HH + 0] + er0;
        float v1 = el[s * HH + 1] + er1;
        float v2 = el[s * HH + 2] + er2;
        v0 = v0 > 0.f ? v0 : 0.2f * v0;
        v1 = v1 > 0.f ? v1 : 0.2f * v1;
        v2 = v2 > 0.f ? v2 : 0.2f * v2;
        aebuf[(size_t)(s0 + i) * HH + 0] = v0;
        aebuf[(size_t)(s0 + i) * HH + 1] = v1;
        aebuf[(size_t)(s0 + i) * HH + 2] = v2;
        m0 = fmaxf(m0, v0); m1 = fmaxf(m1, v1); m2 = fmaxf(m2, v2);
    }
    float d0 = 0.f, d1 = 0.f, d2 = 0.f;
    for (int i = 0; i < deg; ++i) {
        float p0 = expf(aebuf[(size_t)(s0 + i) * HH + 0] - m0);
        float p1 = expf(aebuf[(size_t)(s0 + i) * HH + 1] - m1);
        float p2 = expf(aebuf[(size_t)(s0 + i) * HH + 2] - m2);
        aebuf[(size_t)(s0 + i) * HH + 0] = p0;
        aebuf[(size_t)(s0 + i) * HH + 1] = p1;
        aebuf[(size_t)(s0 + i) * HH + 2] = p2;
        d0 += p0; d1 += p1; d2 += p2;
    }
    const float i0 = 1.f / d0, i1 = 1.f / d1, i2 = 1.f / d2;
    for (int i = 0; i < deg; ++i) {
        float a0 = aebuf[(size_t)(s0 + i) * HH + 0] * i0;
        float a1 = aebuf[(size_t)(s0 + i) * HH + 1] * i1;
        float a2 = aebuf[(size_t)(s0 + i) * HH + 2] * i2;
        aebuf[(size_t)(s0 + i) * HH + 0] = a0;
        aebuf[(size_t)(s0 + i) * HH + 1] = a1;
        aebuf[(size_t)(s0 + i) * HH + 2] = a2;
        if (attn) attn[eorig[s0 + i]] = fmaxf(fmaxf(a0, a1), a2);
    }
}

// ---------------------------------------------------------------- GAT gather + fused epilogue
template <int DH>
__global__ __launch_bounds__(256) void gat_gather(const int* __restrict__ rowstart,
                                                  const int* __restrict__ cnt,
                                                  const int* __restrict__ esrc,
                                                  const float* __restrict__ aebuf,
                                                  const float* __restrict__ z,
                                                  const float* __restrict__ bg,
                                                  float* __restrict__ x, int do_relu) {
    constexpr int CO = HH * DH;
    int n = blockIdx.x * 4 + (threadIdx.x >> 6);
    if (n >= NN) return;
    const int lane = threadIdx.x & 63;
    const int s0 = rowstart[n];
    const int deg = cnt[n];
    float a0 = 0.f, a1 = 0.f, a2 = 0.f;
    for (int i = 0; i < deg; ++i) {
        int s = esrc[s0 + i];
        float w0 = aebuf[(size_t)(s0 + i) * HH + 0];
        float w1 = aebuf[(size_t)(s0 + i) * HH + 1];
        float w2 = aebuf[(size_t)(s0 + i) * HH + 2];
        const float* zr = z + (size_t)s * CO;
        if (lane < DH) {
            a0 += w0 * zr[lane];
            a1 += w1 * zr[DH + lane];
            a2 += w2 * zr[2 * DH + lane];
        }
    }
    if (lane < DH) {
        float m = fmaxf(fmaxf(a0 + bg[lane], a1 + bg[DH + lane]), a2 + bg[2 * DH + lane]);
        if (do_relu) m = fmaxf(m, 0.f);
        x[(size_t)n * DH + lane] = m;
    }
}

// ---------------------------------------------------------------- GCN gather (atomic-free)
template <int K>
__global__ __launch_bounds__(256) void gcn_gather(const int* __restrict__ rowstart,
                                                  const int* __restrict__ cnt,
                                                  const int* __restrict__ esrc,
                                                  const float* __restrict__ xin,
                                                  const float* __restrict__ rdout,
                                                  const float* __restrict__ rdin,
                                                  float* __restrict__ agg) {
    int n = blockIdx.x * 4 + (threadIdx.x >> 6);
    if (n >= NN) return;
    const int lane = threadIdx.x & 63;
    const int s0 = rowstart[n];
    const int deg = cnt[n];
    float acc0 = 0.f, acc1 = 0.f;
    for (int i = 0; i < deg; ++i) {
        int s = esrc[s0 + i];
        float sc = rdout[s];
        const float* xr = xin + (size_t)s * K;
        if (lane < K) acc0 += sc * xr[lane];
        if (K > 64 && lane + 64 < K) acc1 += sc * xr[lane + 64];
    }
    const float ri = rdin[n];
    if (lane < K) agg[(size_t)n * K + lane] = acc0 * ri;
    if (K > 64 && lane + 64 < K) agg[(size_t)n * K + lane + 64] = acc1 * ri;
}

// out = relu( in @ W + b ),  (N x K) @ (K x 96); rdin scaling already in `in`.
template <int K>
__global__ __launch_bounds__(192) void gcn_gemm(const float* __restrict__ in,
                                                const float* __restrict__ W,
                                                const float* __restrict__ bias,
                                                float* __restrict__ out) {
    __shared__ float Wl[K * HD];
    __shared__ float hs[RROWS * K];
    __shared__ float bl[HD];
    const int tid = threadIdx.x;
    for (int i = tid; i < K * HD; i += 192) Wl[i] = W[i];
    if (tid < HD) bl[tid] = bias[tid];
    const int base = blockIdx.x * RROWS;
    const int nrow = min(RROWS, NN - base);
    for (int i = tid; i < nrow * K; i += 192) hs[i] = in[(size_t)base * K + i];
    __syncthreads();
    const int co = tid % HD;
    const int grp = tid / HD;  // 0..1, each handles 8 rows
    float acc[8];
#pragma unroll
    for (int j = 0; j < 8; ++j) acc[j] = bl[co];
#pragma unroll 4
    for (int k = 0; k < K; ++k) {
        float w = Wl[k * HD + co];
#pragma unroll
        for (int j = 0; j < 8; ++j) acc[j] += hs[(grp * 8 + j) * K + k] * w;
    }
#pragma unroll
    for (int j = 0; j < 8; ++j) {
        int r = grp * 8 + j;
        if (r < nrow) out[(size_t)(base + r) * HD + co] = fmaxf(acc[j], 0.f);
    }
}

// ---------------------------------------------------------------- pooling + heads
__global__ __launch_bounds__(96) void pool_k(const float* __restrict__ x,
                                             const int* __restrict__ gid,
                                             float* __restrict__ s,
                                             float* __restrict__ c) {
    const int f = threadIdx.x;  // 0..95
    const int n0 = blockIdx.x * PBLK;
    const int n1 = min(n0 + PBLK, NN);
    int cur = gid[n0];
    float acc = 0.f;
    int cnt = 0;
    for (int n = n0; n < n1; ++n) {
        int g = gid[n];  // wave-uniform
        if (g != cur) {
            unsafeAtomicAdd(&s[cur * HD + f], acc);
            if (f == 0) unsafeAtomicAdd(&c[cur], (float)cnt);
            acc = 0.f;
            cnt = 0;
            cur = g;
        }
        acc += x[(size_t)n * HD + f];
        ++cnt;
    }
    unsafeAtomicAdd(&s[cur * HD + f], acc);
    if (f == 0) unsafeAtomicAdd(&c[cur], (float)cnt);
}

__global__ void weight_k(const float* __restrict__ x3, float* __restrict__ w) {
    int n = blockIdx.x * blockDim.x + threadIdx.x;
    if (n >= NN) return;
    w[n] = x3[(size_t)n * HD + 78];
}

__global__ __launch_bounds__(96) void final_k(
    const float* __restrict__ s1, const float* __restrict__ s2, const float* __restrict__ s3,
    const float* __restrict__ c1, const float* __restrict__ c2, const float* __restrict__ c3,
    const float* __restrict__ Wr1, const float* __restrict__ br1,
    const float* __restrict__ Wr2, const float* __restrict__ br2,
    const float* __restrict__ Wcl, const float* __restrict__ bcl,
    float* __restrict__ r1, float* __restrict__ r2, float* __restrict__ cls,
    float* __restrict__ hg3) {
    __shared__ float sh[HD];
    int g = blockIdx.x, f = threadIdx.x;
    float h1v = s1[g * HD + f] / fmaxf(c1[g], 1.f);
    float h2v = s2[g * HD + f] / fmaxf(c2[g], 1.f);
    float h3v = s3[g * HD + f] / fmaxf(c3[g], 1.f);
    hg3[g * HD + f] = h3v;
    sh[f] = h1v * Wr1[f];
    __syncthreads();
    if (f == 0) {
        float t = 0.f;
        for (int i = 0; i < HD; ++i) t += sh[i];
        r1[g] = t + br1[0];
    }
    __syncthreads();
    sh[f] = h2v * Wr2[f];
    __syncthreads();
    if (f == 0) {
        float t = 0.f;
        for (int i = 0; i < HD; ++i) t += sh[i];
        r2[g] = t + br2[0];
    }
    __syncthreads();
    for (int c = 0; c < 10; ++c) {
        sh[f] = h3v * Wcl[f * 10 + c];
        __syncthreads();
        if (f == 0) {
            float t = 0.f;
            for (int i = 0; i < HD; ++i) t += sh[i];
            cls[g * 10 + c] = t + bcl[c];
        }
        __syncthreads();
    }
}

// ---------------------------------------------------------------- host side

struct WS {
    float *z, *xbuf, *ybuf, *el, *er, *aebuf, *rdout, *rdin, *wal, *war;
    int *cin, *cout, *rowstart, *cursor, *esrc, *eorig, *bsum, *boff;
};

template <int DH>
static void run_graph(const float* h, const int* src, const int* dst, const int* gid,
                      const float* Wg, const float* al, const float* ar, const float* bg,
                      const float* Wf, const float* bf, const float* W2, const float* b2,
                      int relu_epi, float* attn, float* pool_s, float* pool_c,
                      const WS& w, hipStream_t st) {
    const int nb = (NN + RROWS - 1) / RROWS;
    const int eb = (NE + 255) / 256;
    const int nb256 = (NN + 255) / 256;
    const int wb = (NN + 3) / 4;  // wave-per-node blocks

    gatz_gemm<DH, DH><<<NN / 64, 192, 0, st>>>(h, Wg, w.z);
    waler_k<DH, DH><<<1, 192, 0, st>>>(Wg, al, ar, w.wal, w.war);
    el_er_k<DH><<<(NN + 127) / 128, 128, 0, st>>>(h, w.wal, w.war, w.el, w.er);

    // CSR build (dst-sorted) + degrees
    hipMemsetAsync(w.cin, 0, NN * sizeof(int), st);
    hipMemsetAsync(w.cout, 0, NN * sizeof(int), st);
    hist_k<<<eb, 256, 0, st>>>(src, dst, w.cin, w.cout);
    scan1_k<<<NSB, SCB, 0, st>>>(w.cin, w.bsum);
    scan2_k<<<1, SCB, 0, st>>>(w.bsum, w.boff);
    scan3_k<<<NSB, SCB, 0, st>>>(w.cin, w.boff, w.rowstart, w.cursor);
    fill_k<<<eb, 256, 0, st>>>(src, dst, w.cursor, w.esrc, w.eorig);
    rsqrt_k<<<nb256, 256, 0, st>>>(w.cin, w.cout, w.rdin, w.rdout);

    gat_softmax<<<nb256, 256, 0, st>>>(w.rowstart, w.cin, w.esrc, w.eorig,
                                       w.el, w.er, w.aebuf, attn);
    gat_gather<DH><<<wb, 256, 0, st>>>(w.rowstart, w.cin, w.esrc, w.aebuf, w.z,
                                       bg, w.xbuf, relu_epi);

    // GCN layer 1: xbuf (width DH) -> ybuf (width DH, rdin-scaled) -> xbuf (96)
    gcn_gather<DH><<<wb, 256, 0, st>>>(w.rowstart, w.cin, w.esrc, w.xbuf,
                                       w.rdout, w.rdin, w.ybuf);
    gcn_gemm<DH><<<nb, 192, 0, st>>>(w.ybuf, Wf, bf, w.xbuf);
    // GCN layer 2: xbuf (96) -> ybuf (96) -> xbuf (96)
    gcn_gather<HD><<<wb, 256, 0, st>>>(w.rowstart, w.cin, w.esrc, w.xbuf,
                                       w.rdout, w.rdin, w.ybuf);
    gcn_gemm<HD><<<nb, 192, 0, st>>>(w.ybuf, W2, b2, w.xbuf);

    hipMemsetAsync(pool_s, 0, NG * HD * sizeof(float), st);
    hipMemsetAsync(pool_c, 0, NG * sizeof(float), st);
    pool_k<<<(NN + PBLK - 1) / PBLK, 96, 0, st>>>(w.xbuf, gid, pool_s, pool_c);
}

extern "C" void kernel_launch(void* const* d_in, const int* in_sizes, int n_in,
                              void* d_out, int out_size, void* d_ws, size_t ws_size,
                              hipStream_t stream) {
    (void)in_sizes; (void)n_in; (void)out_size; (void)ws_size;
    const float* h1 = (const float*)d_in[0];
    const float* h2 = (const float*)d_in[1];
    const float* h3 = (const float*)d_in[2];
    const int* src1 = (const int*)d_in[3];
    const int* dst1 = (const int*)d_in[4];
    const int* gid1 = (const int*)d_in[5];
    const int* src2 = (const int*)d_in[6];
    const int* dst2 = (const int*)d_in[7];
    const int* gid2 = (const int*)d_in[8];
    const int* src3 = (const int*)d_in[9];
    const int* dst3 = (const int*)d_in[10];
    const int* gid3 = (const int*)d_in[11];
    const float* Wg1 = (const float*)d_in[12];
    const float* al1 = (const float*)d_in[13];
    const float* ar1 = (const float*)d_in[14];
    const float* bg1 = (const float*)d_in[15];
    const float* Wg2 = (const float*)d_in[16];
    const float* al2 = (const float*)d_in[17];
    const float* ar2 = (const float*)d_in[18];
    const float* bg2 = (const float*)d_in[19];
    const float* Wc1 = (const float*)d_in[20];
    const float* bc1 = (const float*)d_in[21];
    const float* Wc2 = (const float*)d_in[22];
    const float* bc2 = (const float*)d_in[23];
    const float* Wc3 = (const float*)d_in[24];
    const float* bc3 = (const float*)d_in[25];
    const float* Wr1 = (const float*)d_in[26];
    const float* br1 = (const float*)d_in[27];
    const float* Wr2 = (const float*)d_in[28];
    const float* br2 = (const float*)d_in[29];
    const float* Wcl = (const float*)d_in[30];
    const float* bcl = (const float*)d_in[31];

    float* out = (float*)d_out;
    float* o_r1 = out + 0;
    float* o_r2 = out + 100;
    float* o_cls = out + 200;
    float* o_attn1 = out + 1200;
    float* o_attn3 = out + 401200;
    float* o_weight = out + 801200;
    float* o_hg3 = out + 841200;

    // workspace layout
    float* ws = (float*)d_ws;
    size_t off = 0;
    WS w;
    w.z = ws + off;     off += (size_t)NN * 192;
    w.xbuf = ws + off;  off += (size_t)NN * HD;
    w.ybuf = ws + off;  off += (size_t)NN * HD;
    w.el = ws + off;    off += (size_t)NN * HH;
    w.er = ws + off;    off += (size_t)NN * HH;
    w.aebuf = ws + off; off += (size_t)NE * HH;
    w.rdout = ws + off; off += NN;
    w.rdin = ws + off;  off += NN;
    w.wal = ws + off;   off += 192;
    w.war = ws + off;   off += 192;
    float* s1 = ws + off; off += NG * HD;
    float* s2 = ws + off; off += NG * HD;
    float* s3 = ws + off; off += NG * HD;
    float* c1 = ws + off; off += NG;
    float* c2 = ws + off; off += NG;
    float* c3 = ws + off; off += NG;
    w.cin = (int*)(ws + off);      off += NN;
    w.cout = (int*)(ws + off);     off += NN;
    w.rowstart = (int*)(ws + off); off += NN;
    w.cursor = (int*)(ws + off);   off += NN;
    w.esrc = (int*)(ws + off);     off += NE;
    w.eorig = (int*)(ws + off);    off += NE;
    w.bsum = (int*)(ws + off);     off += NSB;
    w.boff = (int*)(ws + off);     off += NSB;

    // graph 1: GAT(Wg1, Dh=63) -> relu(max) -> GCN(Wc3) -> GCN(Wc2), attn out
    run_graph<63>(h1, src1, dst1, gid1, Wg1, al1, ar1, bg1, Wc3, bc3, Wc2, bc2,
                  1, o_attn1, s1, c1, w, stream);
    // graph 2: same GAT weights, no relu on max, no attn out
    run_graph<63>(h2, src2, dst2, gid2, Wg1, al1, ar1, bg1, Wc3, bc3, Wc2, bc2,
                  0, nullptr, s2, c2, w, stream);
    // graph 3: GAT(Wg2, Dh=64), no relu on max, attn out; GCN(Wc1) then GCN(Wc2)
    run_graph<64>(h3, src3, dst3, gid3, Wg2, al2, ar2, bg2, Wc1, bc1, Wc2, bc2,
                  0, o_attn3, s3, c3, w, stream);

    weight_k<<<(NN + 255) / 256, 256, 0, stream>>>(w.xbuf, o_weight);
    final_k<<<NG, 96, 0, stream>>>(s1, s2, s3, c1, c2, c3, Wr1, br1, Wr2, br2,
                                   Wcl, bcl, o_r1, o_r2, o_cls, o_hg3);
}

// Round 12
// 1180.486 us; speedup vs baseline: 3.7377x; 1.1310x over previous
//
#include <hip/hip_runtime.h>

#define NN 40000
#define NE 400000
#define NG 100
#define HH 3
#define HD 96

static constexpr int RROWS = 16;  // rows per block in node GEMMs
static constexpr int PBLK = 128;  // nodes per block in pool_k
static constexpr int SCB = 256;   // scan block size
static constexpr int NSB = (NN + SCB - 1) / SCB;  // 157 scan blocks

// ---------------------------------------------------------------- GAT z GEMM (register-tiled)
// z = h @ Wg  (N x DIN) @ (DIN x 3*DH). Block = 64 rows x 192 cols, 192 threads,
// each thread an 8x8 register tile (cols interleaved at stride 24).
// v2: W staged in two 32-k chunks -> LDS 41.2 KB -> 3 blocks/CU.
template <int DIN, int DH>
__global__ __launch_bounds__(192) void gatz_gemm(const float* __restrict__ h,
                                                 const float* __restrict__ W,
                                                 float* __restrict__ z) {
    constexpr int CO = HH * DH;   // 189 or 192
    constexpr int COP = 192;      // padded col count (= blockDim)
    constexpr int KP = 64;        // padded K
    constexpr int KC = 32;        // K staging chunk
    constexpr int HSTR = 65;      // hsl row stride (65%32=1 -> conflict-free)
    __shared__ float Wl[KC * COP];    // 24576 B
    __shared__ float hsl[64 * HSTR];  // 16640 B
    const int tid = threadIdx.x;
    const int base = blockIdx.x * 64;
#pragma unroll 1
    for (int idx = tid; idx < 64 * KP; idx += 192) {
        int r = idx >> 6, k = idx & 63;
        hsl[r * HSTR + k] = (k < DIN) ? h[(size_t)(base + r) * DIN + k] : 0.f;
    }
    const int rt = tid / 24;  // 0..7 -> rows rt*8..rt*8+7
    const int ct = tid % 24;  // cols ct + 24*j, j=0..7
    const int r0 = rt * 8;
    float acc[8][8];
#pragma unroll
    for (int i = 0; i < 8; ++i)
#pragma unroll
        for (int j = 0; j < 8; ++j) acc[i][j] = 0.f;
#pragma unroll 1
    for (int kc = 0; kc < KP / KC; ++kc) {
        __syncthreads();  // kc=0: hsl ready; kc>0: all waves done reading Wl
#pragma unroll 4
        for (int k = 0; k < KC; ++k) {
            const int kg = kc * KC + k;
            Wl[k * COP + tid] = (kg < DIN && tid < CO) ? W[kg * CO + tid] : 0.f;
        }
        __syncthreads();
#pragma unroll 2
        for (int k = 0; k < KC; ++k) {
            float hv[8], wv[8];
#pragma unroll
            for (int i = 0; i < 8; ++i) hv[i] = hsl[(r0 + i) * HSTR + kc * KC + k];
#pragma unroll
            for (int j = 0; j < 8; ++j) wv[j] = Wl[k * COP + ct + 24 * j];
#pragma unroll
            for (int i = 0; i < 8; ++i)
#pragma unroll
                for (int j = 0; j < 8; ++j) acc[i][j] += hv[i] * wv[j];
        }
    }
#pragma unroll
    for (int i = 0; i < 8; ++i) {
        const size_t row = base + r0 + i;
#pragma unroll
        for (int j = 0; j < 8; ++j) {
            int c = ct + 24 * j;
            if (c < CO) z[row * CO + c] = acc[i][j];
        }
    }
}

// Wal[k][h] = sum_d W[k][h*DH+d]*al[h][d]  (folds el = z@al into h@(W@al))
template <int DIN, int DH>
__global__ __launch_bounds__(192) void waler_k(const float* __restrict__ W,
                                               const float* __restrict__ al,
                                               const float* __restrict__ ar,
                                               float* __restrict__ Wal,
                                               float* __restrict__ War) {
    constexpr int CO = HH * DH;
    const int t = threadIdx.x;
    if (t >= DIN * HH) return;
    const int k = t / HH, hd = t % HH;
    float sl = 0.f, sr = 0.f;
    for (int d = 0; d < DH; ++d) {
        float wv = W[k * CO + hd * DH + d];
        sl += wv * al[hd * DH + d];
        sr += wv * ar[hd * DH + d];
    }
    Wal[k * HH + hd] = sl;
    War[k * HH + hd] = sr;
}

// el[n][h] = h[n] . Wal[:,h] ; er likewise.
template <int DIN>
__global__ __launch_bounds__(128) void el_er_k(const float* __restrict__ h,
                                               const float* __restrict__ Wal,
                                               const float* __restrict__ War,
                                               float* __restrict__ el,
                                               float* __restrict__ er) {
    constexpr int STR = (DIN % 2 == 0) ? DIN + 1 : DIN;  // 63->63, 64->65
    __shared__ float hsl[128 * STR];
    __shared__ float walS[DIN * HH], warS[DIN * HH];
    const int t = threadIdx.x;
    const int base = blockIdx.x * 128;
    const int nrow = min(128, NN - base);
    for (int idx = t; idx < nrow * DIN; idx += 128) {
        int r = idx / DIN, k = idx - r * DIN;
        hsl[r * STR + k] = h[(size_t)base * DIN + idx];
    }
    for (int idx = t; idx < DIN * HH; idx += 128) {
        walS[idx] = Wal[idx];
        warS[idx] = War[idx];
    }
    __syncthreads();
    if (t >= nrow) return;
    float e0 = 0.f, e1 = 0.f, e2 = 0.f, f0 = 0.f, f1 = 0.f, f2 = 0.f;
    for (int k = 0; k < DIN; ++k) {
        float hv = hsl[t * STR + k];
        e0 += hv * walS[k * HH + 0];
        e1 += hv * walS[k * HH + 1];
        e2 += hv * walS[k * HH + 2];
        f0 += hv * warS[k * HH + 0];
        f1 += hv * warS[k * HH + 1];
        f2 += hv * warS[k * HH + 2];
    }
    const int n = base + t;
    el[n * HH + 0] = e0; el[n * HH + 1] = e1; el[n * HH + 2] = e2;
    er[n * HH + 0] = f0; er[n * HH + 1] = f1; er[n * HH + 2] = f2;
}

// ---------------------------------------------------------------- CSR build
__global__ void hist_k(const int* __restrict__ src, const int* __restrict__ dst,
                       int* __restrict__ cin, int* __restrict__ cout) {
    int e = blockIdx.x * blockDim.x + threadIdx.x;
    if (e >= NE) return;
    atomicAdd(&cin[dst[e]], 1);
    atomicAdd(&cout[src[e]], 1);
}

// 3-phase device-wide exclusive scan of cin -> rowstart (+cursor).
__global__ __launch_bounds__(SCB) void scan1_k(const int* __restrict__ cin,
                                               int* __restrict__ bsum) {
    __shared__ int sh[SCB];
    const int t = threadIdx.x;
    const int i = blockIdx.x * SCB + t;
    sh[t] = (i < NN) ? cin[i] : 0;
    __syncthreads();
    for (int o = SCB / 2; o > 0; o >>= 1) {
        if (t < o) sh[t] += sh[t + o];
        __syncthreads();
    }
    if (t == 0) bsum[blockIdx.x] = sh[0];
}

__global__ __launch_bounds__(SCB) void scan2_k(const int* __restrict__ bsum,
                                               int* __restrict__ boff) {
    __shared__ int sh[SCB];
    const int t = threadIdx.x;
    int v = (t < NSB) ? bsum[t] : 0;
    sh[t] = v;
    __syncthreads();
    for (int o = 1; o < SCB; o <<= 1) {
        int u = (t >= o) ? sh[t - o] : 0;
        __syncthreads();
        sh[t] += u;
        __syncthreads();
    }
    if (t < NSB) boff[t] = sh[t] - v;  // exclusive
}

__global__ __launch_bounds__(SCB) void scan3_k(const int* __restrict__ cin,
                                               const int* __restrict__ boff,
                                               int* __restrict__ rowstart,
                                               int* __restrict__ cursor) {
    __shared__ int sh[SCB];
    const int t = threadIdx.x;
    const int i = blockIdx.x * SCB + t;
    int v = (i < NN) ? cin[i] : 0;
    sh[t] = v;
    __syncthreads();
    for (int o = 1; o < SCB; o <<= 1) {
        int u = (t >= o) ? sh[t - o] : 0;
        __syncthreads();
        sh[t] += u;
        __syncthreads();
    }
    if (i < NN) {
        int rs = boff[blockIdx.x] + sh[t] - v;  // exclusive prefix
        rowstart[i] = rs;
        cursor[i] = rs;
    }
}

__global__ void fill_k(const int* __restrict__ src, const int* __restrict__ dst,
                       int* __restrict__ cursor, int* __restrict__ esrc,
                       int* __restrict__ eorig) {
    int e = blockIdx.x * blockDim.x + threadIdx.x;
    if (e >= NE) return;
    int pos = atomicAdd(&cursor[dst[e]], 1);
    esrc[pos] = src[e];
    eorig[pos] = e;
}

__global__ void rsqrt_k(const int* __restrict__ cin, const int* __restrict__ cout,
                        float* __restrict__ rdin, float* __restrict__ rdout) {
    int n = blockIdx.x * blockDim.x + threadIdx.x;
    if (n >= NN) return;
    rdin[n] = 1.f / sqrtf((float)max(cin[n], 1));
    rdout[n] = 1.f / sqrtf((float)max(cout[n], 1));
}

// ---------------------------------------------------------------- GAT softmax (per dst node, serial over CSR row)
__global__ void gat_softmax(const int* __restrict__ rowstart, const int* __restrict__ cnt,
                            const int* __restrict__ esrc, const int* __restrict__ eorig,
                            const float* __restrict__ el, const float* __restrict__ er,
                            float* __restrict__ aebuf, float* __restrict__ attn) {
    int n = blockIdx.x * blockDim.x + threadIdx.x;
    if (n >= NN) return;
    const int s0 = rowstart[n];
    const int deg = cnt[n];
    if (deg == 0) return;
    const float er0 = er[n * HH + 0], er1 = er[n * HH + 1], er2 = er[n * HH + 2];
    float m0 = -3.4e38f, m1 = -3.4e38f, m2 = -3.4e38f;
    for (int i = 0; i < deg; ++i) {
        int s = esrc[s0 + i];
        float v0 = el[s * HH + 0] + er0;
        float v1 = el[s * HH + 1] + er1;
        float v2 = el[s * HH + 2] + er2;
        v0 = v0 > 0.f ? v0 : 0.2f * v0;
        v1 = v1 > 0.f ? v1 : 0.2f * v1;
        v2 = v2 > 0.f ? v2 : 0.2f * v2;
        aebuf[(size_t)(s0 + i) * HH + 0] = v0;
        aebuf[(size_t)(s0 + i) * HH + 1] = v1;
        aebuf[(size_t)(s0 + i) * HH + 2] = v2;
        m0 = fmaxf(m0, v0); m1 = fmaxf(m1, v1); m2 = fmaxf(m2, v2);
    }
    float d0 = 0.f, d1 = 0.f, d2 = 0.f;
    for (int i = 0; i < deg; ++i) {
        float p0 = expf(aebuf[(size_t)(s0 + i) * HH + 0] - m0);
        float p1 = expf(aebuf[(size_t)(s0 + i) * HH + 1] - m1);
        float p2 = expf(aebuf[(size_t)(s0 + i) * HH + 2] - m2);
        aebuf[(size_t)(s0 + i) * HH + 0] = p0;
        aebuf[(size_t)(s0 + i) * HH + 1] = p1;
        aebuf[(size_t)(s0 + i) * HH + 2] = p2;
        d0 += p0; d1 += p1; d2 += p2;
    }
    const float i0 = 1.f / d0, i1 = 1.f / d1, i2 = 1.f / d2;
    for (int i = 0; i < deg; ++i) {
        float a0 = aebuf[(size_t)(s0 + i) * HH + 0] * i0;
        float a1 = aebuf[(size_t)(s0 + i) * HH + 1] * i1;
        float a2 = aebuf[(size_t)(s0 + i) * HH + 2] * i2;
        aebuf[(size_t)(s0 + i) * HH + 0] = a0;
        aebuf[(size_t)(s0 + i) * HH + 1] = a1;
        aebuf[(size_t)(s0 + i) * HH + 2] = a2;
        if (attn) attn[eorig[s0 + i]] = fmaxf(fmaxf(a0, a1), a2);
    }
}

// ---------------------------------------------------------------- GAT gather + fused epilogue
// v2: 4-edge unrolled main loop. v1 was memory-latency-bound (58 us,
// VALUBusy 13.7%, Occ 60%, ~4 loads in flight); 4-wide gives ~16.
template <int DH>
__global__ __launch_bounds__(256) void gat_gather(const int* __restrict__ rowstart,
                                                  const int* __restrict__ cnt,
                                                  const int* __restrict__ esrc,
                                                  const float* __restrict__ aebuf,
                                                  const float* __restrict__ z,
                                                  const float* __restrict__ bg,
                                                  float* __restrict__ x, int do_relu) {
    constexpr int CO = HH * DH;
    int n = blockIdx.x * 4 + (threadIdx.x >> 6);
    if (n >= NN) return;
    const int lane = threadIdx.x & 63;
    const int s0 = rowstart[n];
    const int deg = cnt[n];
    const bool act = lane < DH;
    float a0 = 0.f, a1 = 0.f, a2 = 0.f;
    int i = 0;
    for (; i + 4 <= deg; i += 4) {
        const int sA = esrc[s0 + i], sB = esrc[s0 + i + 1];
        const int sC = esrc[s0 + i + 2], sD = esrc[s0 + i + 3];
        const float* wA = aebuf + (size_t)(s0 + i) * HH;
        const float wA0 = wA[0], wA1 = wA[1], wA2 = wA[2];
        const float wB0 = wA[3], wB1 = wA[4], wB2 = wA[5];
        const float wC0 = wA[6], wC1 = wA[7], wC2 = wA[8];
        const float wD0 = wA[9], wD1 = wA[10], wD2 = wA[11];
        const float* zA = z + (size_t)sA * CO;
        const float* zB = z + (size_t)sB * CO;
        const float* zC = z + (size_t)sC * CO;
        const float* zD = z + (size_t)sD * CO;
        if (act) {
            const float zA0 = zA[lane], zA1 = zA[DH + lane], zA2 = zA[2 * DH + lane];
            const float zB0 = zB[lane], zB1 = zB[DH + lane], zB2 = zB[2 * DH + lane];
            const float zC0 = zC[lane], zC1 = zC[DH + lane], zC2 = zC[2 * DH + lane];
            const float zD0 = zD[lane], zD1 = zD[DH + lane], zD2 = zD[2 * DH + lane];
            a0 += wA0 * zA0 + wB0 * zB0 + wC0 * zC0 + wD0 * zD0;
            a1 += wA1 * zA1 + wB1 * zB1 + wC1 * zC1 + wD1 * zD1;
            a2 += wA2 * zA2 + wB2 * zB2 + wC2 * zC2 + wD2 * zD2;
        }
    }
    for (; i < deg; ++i) {
        const int s = esrc[s0 + i];
        const float w0 = aebuf[(size_t)(s0 + i) * HH + 0];
        const float w1 = aebuf[(size_t)(s0 + i) * HH + 1];
        const float w2 = aebuf[(size_t)(s0 + i) * HH + 2];
        const float* zr = z + (size_t)s * CO;
        if (act) {
            a0 += w0 * zr[lane];
            a1 += w1 * zr[DH + lane];
            a2 += w2 * zr[2 * DH + lane];
        }
    }
    if (act) {
        float m = fmaxf(fmaxf(a0 + bg[lane], a1 + bg[DH + lane]), a2 + bg[2 * DH + lane]);
        if (do_relu) m = fmaxf(m, 0.f);
        x[(size_t)n * DH + lane] = m;
    }
}

// ---------------------------------------------------------------- GCN gather (atomic-free)
// v2: 4-edge unrolled (same latency-hiding rationale as gat_gather).
template <int K>
__global__ __launch_bounds__(256) void gcn_gather(const int* __restrict__ rowstart,
                                                  const int* __restrict__ cnt,
                                                  const int* __restrict__ esrc,
                                                  const float* __restrict__ xin,
                                                  const float* __restrict__ rdout,
                                                  const float* __restrict__ rdin,
                                                  float* __restrict__ agg) {
    int n = blockIdx.x * 4 + (threadIdx.x >> 6);
    if (n >= NN) return;
    const int lane = threadIdx.x & 63;
    const int s0 = rowstart[n];
    const int deg = cnt[n];
    const bool act0 = lane < K;
    const bool act1 = (K > 64) && (lane + 64 < K);
    float acc0 = 0.f, acc1 = 0.f;
    int i = 0;
    for (; i + 4 <= deg; i += 4) {
        const int sA = esrc[s0 + i], sB = esrc[s0 + i + 1];
        const int sC = esrc[s0 + i + 2], sD = esrc[s0 + i + 3];
        const float scA = rdout[sA], scB = rdout[sB];
        const float scC = rdout[sC], scD = rdout[sD];
        const float* xA = xin + (size_t)sA * K;
        const float* xB = xin + (size_t)sB * K;
        const float* xC = xin + (size_t)sC * K;
        const float* xD = xin + (size_t)sD * K;
        if (act0)
            acc0 += scA * xA[lane] + scB * xB[lane] + scC * xC[lane] + scD * xD[lane];
        if (act1)
            acc1 += scA * xA[lane + 64] + scB * xB[lane + 64] +
                    scC * xC[lane + 64] + scD * xD[lane + 64];
    }
    for (; i < deg; ++i) {
        const int s = esrc[s0 + i];
        const float sc = rdout[s];
        const float* xr = xin + (size_t)s * K;
        if (act0) acc0 += sc * xr[lane];
        if (act1) acc1 += sc * xr[lane + 64];
    }
    const float ri = rdin[n];
    if (act0) agg[(size_t)n * K + lane] = acc0 * ri;
    if (act1) agg[(size_t)n * K + lane + 64] = acc1 * ri;
}

// out = relu( in @ W + b ),  (N x K) @ (K x 96); rdin scaling already in `in`.
template <int K>
__global__ __launch_bounds__(192) void gcn_gemm(const float* __restrict__ in,
                                                const float* __restrict__ W,
                                                const float* __restrict__ bias,
                                                float* __restrict__ out) {
    __shared__ float Wl[K * HD];
    __shared__ float hs[RROWS * K];
    __shared__ float bl[HD];
    const int tid = threadIdx.x;
    for (int i = tid; i < K * HD; i += 192) Wl[i] = W[i];
    if (tid < HD) bl[tid] = bias[tid];
    const int base = blockIdx.x * RROWS;
    const int nrow = min(RROWS, NN - base);
    for (int i = tid; i < nrow * K; i += 192) hs[i] = in[(size_t)base * K + i];
    __syncthreads();
    const int co = tid % HD;
    const int grp = tid / HD;  // 0..1, each handles 8 rows
    float acc[8];
#pragma unroll
    for (int j = 0; j < 8; ++j) acc[j] = bl[co];
#pragma unroll 4
    for (int k = 0; k < K; ++k) {
        float w = Wl[k * HD + co];
#pragma unroll
        for (int j = 0; j < 8; ++j) acc[j] += hs[(grp * 8 + j) * K + k] * w;
    }
#pragma unroll
    for (int j = 0; j < 8; ++j) {
        int r = grp * 8 + j;
        if (r < nrow) out[(size_t)(base + r) * HD + co] = fmaxf(acc[j], 0.f);
    }
}

// ---------------------------------------------------------------- pooling + heads
__global__ __launch_bounds__(96) void pool_k(const float* __restrict__ x,
                                             const int* __restrict__ gid,
                                             float* __restrict__ s,
                                             float* __restrict__ c) {
    const int f = threadIdx.x;  // 0..95
    const int n0 = blockIdx.x * PBLK;
    const int n1 = min(n0 + PBLK, NN);
    int cur = gid[n0];
    float acc = 0.f;
    int cnt = 0;
    for (int n = n0; n < n1; ++n) {
        int g = gid[n];  // wave-uniform
        if (g != cur) {
            unsafeAtomicAdd(&s[cur * HD + f], acc);
            if (f == 0) unsafeAtomicAdd(&c[cur], (float)cnt);
            acc = 0.f;
            cnt = 0;
            cur = g;
        }
        acc += x[(size_t)n * HD + f];
        ++cnt;
    }
    unsafeAtomicAdd(&s[cur * HD + f], acc);
    if (f == 0) unsafeAtomicAdd(&c[cur], (float)cnt);
}

__global__ void weight_k(const float* __restrict__ x3, float* __restrict__ w) {
    int n = blockIdx.x * blockDim.x + threadIdx.x;
    if (n >= NN) return;
    w[n] = x3[(size_t)n * HD + 78];
}

__global__ __launch_bounds__(96) void final_k(
    const float* __restrict__ s1, const float* __restrict__ s2, const float* __restrict__ s3,
    const float* __restrict__ c1, const float* __restrict__ c2, const float* __restrict__ c3,
    const float* __restrict__ Wr1, const float* __restrict__ br1,
    const float* __restrict__ Wr2, const float* __restrict__ br2,
    const float* __restrict__ Wcl, const float* __restrict__ bcl,
    float* __restrict__ r1, float* __restrict__ r2, float* __restrict__ cls,
    float* __restrict__ hg3) {
    __shared__ float sh[HD];
    int g = blockIdx.x, f = threadIdx.x;
    float h1v = s1[g * HD + f] / fmaxf(c1[g], 1.f);
    float h2v = s2[g * HD + f] / fmaxf(c2[g], 1.f);
    float h3v = s3[g * HD + f] / fmaxf(c3[g], 1.f);
    hg3[g * HD + f] = h3v;
    sh[f] = h1v * Wr1[f];
    __syncthreads();
    if (f == 0) {
        float t = 0.f;
        for (int i = 0; i < HD; ++i) t += sh[i];
        r1[g] = t + br1[0];
    }
    __syncthreads();
    sh[f] = h2v * Wr2[f];
    __syncthreads();
    if (f == 0) {
        float t = 0.f;
        for (int i = 0; i < HD; ++i) t += sh[i];
        r2[g] = t + br2[0];
    }
    __syncthreads();
    for (int c = 0; c < 10; ++c) {
        sh[f] = h3v * Wcl[f * 10 + c];
        __syncthreads();
        if (f == 0) {
            float t = 0.f;
            for (int i = 0; i < HD; ++i) t += sh[i];
            cls[g * 10 + c] = t + bcl[c];
        }
        __syncthreads();
    }
}

// ---------------------------------------------------------------- host side

struct WS {
    float *z, *xbuf, *ybuf, *el, *er, *aebuf, *rdout, *rdin, *wal, *war;
    int *cin, *cout, *rowstart, *cursor, *esrc, *eorig, *bsum, *boff;
};

template <int DH>
static void run_graph(const float* h, const int* src, const int* dst, const int* gid,
                      const float* Wg, const float* al, const float* ar, const float* bg,
                      const float* Wf, const float* bf, const float* W2, const float* b2,
                      int relu_epi, float* attn, float* pool_s, float* pool_c,
                      const WS& w, hipStream_t st) {
    const int nb = (NN + RROWS - 1) / RROWS;
    const int eb = (NE + 255) / 256;
    const int nb256 = (NN + 255) / 256;
    const int wb = (NN + 3) / 4;  // wave-per-node blocks

    gatz_gemm<DH, DH><<<NN / 64, 192, 0, st>>>(h, Wg, w.z);
    waler_k<DH, DH><<<1, 192, 0, st>>>(Wg, al, ar, w.wal, w.war);
    el_er_k<DH><<<(NN + 127) / 128, 128, 0, st>>>(h, w.wal, w.war, w.el, w.er);

    // CSR build (dst-sorted) + degrees
    hipMemsetAsync(w.cin, 0, NN * sizeof(int), st);
    hipMemsetAsync(w.cout, 0, NN * sizeof(int), st);
    hist_k<<<eb, 256, 0, st>>>(src, dst, w.cin, w.cout);
    scan1_k<<<NSB, SCB, 0, st>>>(w.cin, w.bsum);
    scan2_k<<<1, SCB, 0, st>>>(w.bsum, w.boff);
    scan3_k<<<NSB, SCB, 0, st>>>(w.cin, w.boff, w.rowstart, w.cursor);
    fill_k<<<eb, 256, 0, st>>>(src, dst, w.cursor, w.esrc, w.eorig);
    rsqrt_k<<<nb256, 256, 0, st>>>(w.cin, w.cout, w.rdin, w.rdout);

    gat_softmax<<<nb256, 256, 0, st>>>(w.rowstart, w.cin, w.esrc, w.eorig,
                                       w.el, w.er, w.aebuf, attn);
    gat_gather<DH><<<wb, 256, 0, st>>>(w.rowstart, w.cin, w.esrc, w.aebuf, w.z,
                                       bg, w.xbuf, relu_epi);

    // GCN layer 1: xbuf (width DH) -> ybuf (width DH, rdin-scaled) -> xbuf (96)
    gcn_gather<DH><<<wb, 256, 0, st>>>(w.rowstart, w.cin, w.esrc, w.xbuf,
                                       w.rdout, w.rdin, w.ybuf);
    gcn_gemm<DH><<<nb, 192, 0, st>>>(w.ybuf, Wf, bf, w.xbuf);
    // GCN layer 2: xbuf (96) -> ybuf (96) -> xbuf (96)
    gcn_gather<HD><<<wb, 256, 0, st>>>(w.rowstart, w.cin, w.esrc, w.xbuf,
                                       w.rdout, w.rdin, w.ybuf);
    gcn_gemm<HD><<<nb, 192, 0, st>>>(w.ybuf, W2, b2, w.xbuf);

    hipMemsetAsync(pool_s, 0, NG * HD * sizeof(float), st);
    hipMemsetAsync(pool_c, 0, NG * sizeof(float), st);
    pool_k<<<(NN + PBLK - 1) / PBLK, 96, 0, st>>>(w.xbuf, gid, pool_s, pool_c);
}

extern "C" void kernel_launch(void* const* d_in, const int* in_sizes, int n_in,
                              void* d_out, int out_size, void* d_ws, size_t ws_size,
                              hipStream_t stream) {
    (void)in_sizes; (void)n_in; (void)out_size; (void)ws_size;
    const float* h1 = (const float*)d_in[0];
    const float* h2 = (const float*)d_in[1];
    const float* h3 = (const float*)d_in[2];
    const int* src1 = (const int*)d_in[3];
    const int* dst1 = (const int*)d_in[4];
    const int* gid1 = (const int*)d_in[5];
    const int* src2 = (const int*)d_in[6];
    const int* dst2 = (const int*)d_in[7];
    const int* gid2 = (const int*)d_in[8];
    const int* src3 = (const int*)d_in[9];
    const int* dst3 = (const int*)d_in[10];
    const int* gid3 = (const int*)d_in[11];
    const float* Wg1 = (const float*)d_in[12];
    const float* al1 = (const float*)d_in[13];
    const float* ar1 = (const float*)d_in[14];
    const float* bg1 = (const float*)d_in[15];
    const float* Wg2 = (const float*)d_in[16];
    const float* al2 = (const float*)d_in[17];
    const float* ar2 = (const float*)d_in[18];
    const float* bg2 = (const float*)d_in[19];
    const float* Wc1 = (const float*)d_in[20];
    const float* bc1 = (const float*)d_in[21];
    const float* Wc2 = (const float*)d_in[22];
    const float* bc2 = (const float*)d_in[23];
    const float* Wc3 = (const float*)d_in[24];
    const float* bc3 = (const float*)d_in[25];
    const float* Wr1 = (const float*)d_in[26];
    const float* br1 = (const float*)d_in[27];
    const float* Wr2 = (const float*)d_in[28];
    const float* br2 = (const float*)d_in[29];
    const float* Wcl = (const float*)d_in[30];
    const float* bcl = (const float*)d_in[31];

    float* out = (float*)d_out;
    float* o_r1 = out + 0;
    float* o_r2 = out + 100;
    float* o_cls = out + 200;
    float* o_attn1 = out + 1200;
    float* o_attn3 = out + 401200;
    float* o_weight = out + 801200;
    float* o_hg3 = out + 841200;

    // workspace layout
    float* ws = (float*)d_ws;
    size_t off = 0;
    WS w;
    w.z = ws + off;     off += (size_t)NN * 192;
    w.xbuf = ws + off;  off += (size_t)NN * HD;
    w.ybuf = ws + off;  off += (size_t)NN * HD;
    w.el = ws + off;    off += (size_t)NN * HH;
    w.er = ws + off;    off += (size_t)NN * HH;
    w.aebuf = ws + off; off += (size_t)NE * HH;
    w.rdout = ws + off; off += NN;
    w.rdin = ws + off;  off += NN;
    w.wal = ws + off;   off += 192;
    w.war = ws + off;   off += 192;
    float* s1 = ws + off; off += NG * HD;
    float* s2 = ws + off; off += NG * HD;
    float* s3 = ws + off; off += NG * HD;
    float* c1 = ws + off; off += NG;
    float* c2 = ws + off; off += NG;
    float* c3 = ws + off; off += NG;
    w.cin = (int*)(ws + off);      off += NN;
    w.cout = (int*)(ws + off);     off += NN;
    w.rowstart = (int*)(ws + off); off += NN;
    w.cursor = (int*)(ws + off);   off += NN;
    w.esrc = (int*)(ws + off);     off += NE;
    w.eorig = (int*)(ws + off);    off += NE;
    w.bsum = (int*)(ws + off);     off += NSB;
    w.boff = (int*)(ws + off);     off += NSB;

    // graph 1: GAT(Wg1, Dh=63) -> relu(max) -> GCN(Wc3) -> GCN(Wc2), attn out
    run_graph<63>(h1, src1, dst1, gid1, Wg1, al1, ar1, bg1, Wc3, bc3, Wc2, bc2,
                  1, o_attn1, s1, c1, w, stream);
    // graph 2: same GAT weights, no relu on max, no attn out
    run_graph<63>(h2, src2, dst2, gid2, Wg1, al1, ar1, bg1, Wc3, bc3, Wc2, bc2,
                  0, nullptr, s2, c2, w, stream);
    // graph 3: GAT(Wg2, Dh=64), no relu on max, attn out; GCN(Wc1) then GCN(Wc2)
    run_graph<64>(h3, src3, dst3, gid3, Wg2, al2, ar2, bg2, Wc1, bc1, Wc2, bc2,
                  0, o_attn3, s3, c3, w, stream);

    weight_k<<<(NN + 255) / 256, 256, 0, stream>>>(w.xbuf, o_weight);
    final_k<<<NG, 96, 0, stream>>>(s1, s2, s3, c1, c2, c3, Wr1, br1, Wr2, br2,
                                   Wcl, bcl, o_r1, o_r2, o_cls, o_hg3);
}